// Round 1
// baseline (387.019 us; speedup 1.0000x reference)
//
#include <hip/hip_runtime.h>

#pragma clang fp contract(off)

#define T_CAND 856
#define NW 14          // ceil(856/64)
#define CH 4096        // sort chunk (u64 keys -> 32KB LDS)
#define BSC 128        // iou kernel block

__device__ const int d_HW[5]  = {12800, 3200, 800, 208, 56};
__device__ const int d_K[5]   = {200, 200, 200, 200, 56};
__device__ const int d_OFF[5] = {0, 200, 400, 600, 800};

struct LevelPtrs {
  const float* loc[5];
  const float* cls[5];
  const float* reg[5];
  const int*   img;
};

// descending bitonic sort of a[0..P-1] in LDS; pads must be 0 (sorted last).
__device__ __forceinline__ void bitonic_desc(unsigned long long* a, int P) {
  const int tid = threadIdx.x, nthr = blockDim.x;
  for (int k = 2; k <= P; k <<= 1) {
    for (int j = k >> 1; j > 0; j >>= 1) {
      for (int i = tid; i < P; i += nthr) {
        const int ixj = i ^ j;
        if (ixj > i) {
          const unsigned long long x = a[i], y = a[ixj];
          const bool up = (i & k) == 0;
          const bool sw = up ? (x < y) : (x > y);
          if (sw) { a[i] = y; a[ixj] = x; }
        }
      }
      __syncthreads();
    }
  }
}

// ---------------- Kernel 1: per (batch,level) stable top-K + decode ----------------
__global__ __launch_bounds__(1024) void topk_kernel(LevelPtrs P,
    float* __restrict__ candPoly, float* __restrict__ candSc, unsigned* __restrict__ candValid) {
  __shared__ unsigned long long skey[CH];
  __shared__ unsigned long long best[512];
  const int blk = blockIdx.x;
  const int b = blk / 5, l = blk % 5;
  const int HW = d_HW[l], K = d_K[l], OFF = d_OFF[l];
  const float* cls = P.cls[l] + (size_t)b * HW;
  const float* reg = P.reg[l] + (size_t)b * 8 * HW;
  const float* loc = P.loc[l];
  const int tid = threadIdx.x;
  const int nch = (HW + CH - 1) / CH;

  for (int c = 0; c < nch; ++c) {
    const int base = c * CH;
    for (int t2 = tid; t2 < CH; t2 += 1024) {
      const int idx = base + t2;
      unsigned long long key = 0ULL;
      if (idx < HW) {
        const float x = cls[idx];
        // correctly-rounded f32 sigmoid via double
        const float s = (float)(1.0 / (1.0 + exp(-(double)x)));
        const float m = (s > 0.05f) ? s : 0.0f;   // masked = where(scores>thresh, scores, 0)
        key = ((unsigned long long)__float_as_uint(m) << 32)
            | (unsigned long long)(0xFFFFFFFFu - (unsigned)idx);  // tie -> lower idx first
      }
      skey[t2] = key;
    }
    __syncthreads();
    bitonic_desc(skey, CH);
    if (c == 0) {
      for (int t2 = tid; t2 < 512; t2 += 1024) best[t2] = (t2 < 200) ? skey[t2] : 0ULL;
      __syncthreads();
    } else {
      for (int t2 = tid; t2 < 512; t2 += 1024)
        if (t2 >= 200) best[t2] = (t2 < 400) ? skey[t2 - 200] : 0ULL;
      __syncthreads();
      bitonic_desc(best, 512);
    }
  }

  const float hh = (float)P.img[b * 2 + 0];
  const float ww = (float)P.img[b * 2 + 1];
  const float xmax = ww - 1.0f, ymax = hh - 1.0f;
  for (int t2 = tid; t2 < K; t2 += 1024) {
    const unsigned long long key = best[t2];
    const float val = __uint_as_float((unsigned)(key >> 32));
    const int idx = (int)(0xFFFFFFFFu - (unsigned)(key & 0xFFFFFFFFULL));
    const float lx = loc[idx * 2 + 0], ly = loc[idx * 2 + 1];
    const int go = b * T_CAND + OFF + t2;
#pragma unroll
    for (int q = 0; q < 4; ++q) {
      const float rx = reg[(2 * q + 0) * HW + idx];
      const float ry = reg[(2 * q + 1) * HW + idx];
      const float pxv = fminf(fmaxf(lx - rx, 0.0f), xmax);
      const float pyv = fminf(fmaxf(ly - ry, 0.0f), ymax);
      candPoly[go * 8 + 2 * q + 0] = pxv;
      candPoly[go * 8 + 2 * q + 1] = pyv;
    }
    const bool v = (val > 0.05f);        // bw/bh >= MIN_SIZE(0) always true after clip
    candSc[go]    = v ? sqrtf(val) : 0.0f;
    candValid[go] = v ? 1u : 0u;
  }
}

// ---------------- Kernel 2: per-batch stable descending sort of 856 candidates -----
__global__ __launch_bounds__(1024) void sort_kernel(
    const float* __restrict__ candPoly, const float* __restrict__ candSc,
    const unsigned* __restrict__ candValid,
    float* __restrict__ sPoly, float* __restrict__ sSc, unsigned* __restrict__ sValid) {
  __shared__ unsigned long long key[1024];
  const int b = blockIdx.x, tid = threadIdx.x;
  {
    unsigned long long kk = 0ULL;
    if (tid < T_CAND) {
      const float sc = candSc[b * T_CAND + tid];
      kk = ((unsigned long long)__float_as_uint(sc) << 32)
         | (unsigned long long)(0xFFFFFFFFu - (unsigned)tid);
    }
    key[tid] = kk;
  }
  __syncthreads();
  bitonic_desc(key, 1024);
  if (tid < T_CAND) {
    const unsigned long long kk = key[tid];
    const int gi = (int)(0xFFFFFFFFu - (unsigned)(kk & 0xFFFFFFFFULL));
    sSc[b * T_CAND + tid]    = __uint_as_float((unsigned)(kk >> 32));
    sValid[b * T_CAND + tid] = candValid[b * T_CAND + gi];
#pragma unroll
    for (int q = 0; q < 8; ++q)
      sPoly[(size_t)(b * T_CAND + tid) * 8 + q] = candPoly[(size_t)(b * T_CAND + gi) * 8 + q];
  }
}

// ---------------- Kernel 3: suppression bit-matrix via polygon-clip IoU ------------
// M[(b*T+i)*NW + jw] bit j: IoU(clip A=q[i] by B=q[j]) > 0.5, only for j>i, both valid.
__global__ __launch_bounds__(BSC) void iou_kernel(const float* __restrict__ sPoly,
                                                  const unsigned* __restrict__ sValid,
                                                  unsigned long long* __restrict__ M) {
  __shared__ float VX[2][8][BSC];
  __shared__ float VY[2][8][BSC];
  const int i = blockIdx.y, b = blockIdx.z;
  if (sValid[b * T_CAND + i] == 0u) return;   // row never applied in NMS; skip (uniform)
  const int tid = threadIdx.x;
  const int j = blockIdx.x * BSC + tid;
  const float* Ap = sPoly + (size_t)(b * T_CAND + i) * 8;
  const float ax0 = Ap[0], ay0 = Ap[1], ax1 = Ap[2], ay1 = Ap[3],
              ax2 = Ap[4], ay2 = Ap[5], ax3 = Ap[6], ay3 = Ap[7];
  const int jc = (j < T_CAND) ? j : (T_CAND - 1);
  const float* Bp = sPoly + (size_t)(b * T_CAND + jc) * 8;
  const float bx0 = Bp[0], by0 = Bp[1], bx1 = Bp[2], by1 = Bp[3],
              bx2 = Bp[4], by2 = Bp[5], bx3 = Bp[6], by3 = Bp[7];
  const bool need = (j > i) && (j < T_CAND) && (sValid[b * T_CAND + jc] != 0u);
  bool hit = false;
  if (need) {
    // signed 2*area of B (same term order as reference) -> orientation
    float sB = bx0 * by1 - bx1 * by0;
    sB += bx1 * by2 - bx2 * by1;
    sB += bx2 * by3 - bx3 * by2;
    sB += bx3 * by0 - bx0 * by3;
    const float orient = (sB >= 0.0f) ? 1.0f : -1.0f;

    VX[0][0][tid] = ax0; VY[0][0][tid] = ay0;
    VX[0][1][tid] = ax1; VY[0][1][tid] = ay1;
    VX[0][2][tid] = ax2; VY[0][2][tid] = ay2;
    VX[0][3][tid] = ax3; VY[0][3][tid] = ay3;
    int n = 4;
    const float bex[5] = {bx0, bx1, bx2, bx3, bx0};
    const float bey[5] = {by0, by1, by2, by3, by0};
#pragma unroll
    for (int e = 0; e < 4; ++e) {
      const int src = e & 1, dst = src ^ 1;
      const float p1x = bex[e], p1y = bey[e];
      const float dx = bex[e + 1] - p1x, dy = bey[e + 1] - p1y;
      int cnt = 0;
      int pidx = n - 1;                       // JAX gather clamps (incl. -1 -> 0)
      pidx = pidx < 0 ? 0 : (pidx > 7 ? 7 : pidx);
      float px = VX[src][pidx][tid], py = VY[src][pidx][tid];
      float sp = orient * (dx * (py - p1y) - dy * (px - p1x));
#pragma unroll
      for (int k = 0; k < 8; ++k) {
        const float cx = VX[src][k][tid], cy = VY[src][k][tid];
        const float sc2 = orient * (dx * (cy - p1y) - dy * (cx - p1x));
        const bool cin = (sc2 >= 0.0f), pin = (sp >= 0.0f);
        const float denom = sp - sc2;
        const float dd = (fabsf(denom) > 1e-9f) ? denom : 1e-9f;
        const float t = sp / dd;
        const float ipx = px + t * (cx - px);
        const float ipy = py + t * (cy - py);
        const bool vk = (k < n);
        const bool e1 = vk && (cin != pin);
        if (e1 && cnt < 8) { VX[dst][cnt][tid] = ipx; VY[dst][cnt][tid] = ipy; }
        cnt += e1 ? 1 : 0;                     // cnt may pass 8: writes dropped (mode='drop')
        const bool e2 = vk && cin;
        if (e2 && cnt < 8) { VX[dst][cnt][tid] = cx; VY[dst][cnt][tid] = cy; }
        cnt += e2 ? 1 : 0;
        px = cx; py = cy; sp = sc2;            // prev == V[k-1]; identical value reuse
      }
      n = cnt;
    }
    // shoelace on final buffer (buf 0 after 4 ping-pongs)
    float a = 0.0f;
#pragma unroll
    for (int k = 0; k < 8; ++k) {
      int nxt = (k == n - 1) ? 0 : ((k + 1 > 7) ? 7 : (k + 1));  // clamp like JAX
      const float xk = VX[0][k][tid], yk = VY[0][k][tid];
      const float xn = VX[0][nxt][tid], yn = VY[0][nxt][tid];
      const float term = xk * yn - xn * yk;
      a += (k < n) ? term : 0.0f;
    }
    const float inter = 0.5f * fabsf(a);
    float aA = ax0 * ay1 - ax1 * ay0;
    aA += ax1 * ay2 - ax2 * ay1;
    aA += ax2 * ay3 - ax3 * ay2;
    aA += ax3 * ay0 - ax0 * ay3;
    const float areaA = 0.5f * fabsf(aA);
    const float areaB = 0.5f * fabsf(sB);
    const float uni = areaA + areaB - inter;
    const float iou = inter / fmaxf(uni, 1e-9f);
    hit = iou > 0.5f;
  }
  const unsigned long long ball = __ballot(hit);
  if ((tid & 63) == 0) {
    const int jw = blockIdx.x * (BSC / 64) + (tid >> 6);
    M[(size_t)(b * T_CAND + i) * NW + jw] = ball;
  }
}

// ---------------- Kernel 4: serial greedy NMS (1 wave/batch) + top-100 emit --------
__global__ __launch_bounds__(64) void nms_out_kernel(const unsigned long long* __restrict__ M,
    const float* __restrict__ sPoly, const float* __restrict__ sSc,
    const unsigned* __restrict__ sValid, float* __restrict__ out) {
  const int b = blockIdx.x, lane = threadIdx.x;
  // init keep words from valid flags
  unsigned long long wk = 0ULL;
  for (int w = 0; w < NW; ++w) {
    const int idx = w * 64 + lane;
    const bool v = (idx < T_CAND) && (sValid[b * T_CAND + idx] != 0u);
    const unsigned long long ball = __ballot(v);
    if (lane == w) wk = ball;
  }
  const unsigned long long* Mb = M + (size_t)b * T_CAND * NW;
  const bool ml = lane < NW;
  unsigned long long m[8];
#pragma unroll
  for (int r = 0; r < 8; ++r) m[r] = ml ? Mb[r * NW + lane] : 0ULL;
  for (int g = 0; g < T_CAND; g += 8) {
    unsigned long long nx[8];
    const int g2 = g + 8;
#pragma unroll
    for (int r = 0; r < 8; ++r) nx[r] = (ml && g2 < T_CAND) ? Mb[(size_t)(g2 + r) * NW + lane] : 0ULL;
#pragma unroll
    for (int r = 0; r < 8; ++r) {
      const int i = g + r;
      const int ow = i >> 6, ob = i & 63;
      const unsigned rl = (unsigned)__builtin_amdgcn_readlane((int)(unsigned)(wk & 0xFFFFFFFFULL), ow);
      const unsigned rh = (unsigned)__builtin_amdgcn_readlane((int)(unsigned)(wk >> 32), ow);
      const unsigned bit = (ob < 32) ? ((rl >> ob) & 1u) : ((rh >> (ob - 32)) & 1u);
      wk &= ~(bit ? m[r] : 0ULL);
    }
#pragma unroll
    for (int r = 0; r < 8; ++r) m[r] = nx[r];
  }
  __shared__ unsigned long long keepw[NW];
  if (lane < NW) keepw[lane] = wk;
  __syncthreads();
  int totalKeep = 0;
  for (int w = 0; w < NW; ++w) totalKeep += __popcll(keepw[w]);

  for (int o = lane; o < 100; o += 64) {
    const bool kept = o < totalKeep;
    int idx = 0;
    if (kept) {
      int r = o, w = 0;
      unsigned long long word = 0ULL;
      for (; w < NW; ++w) {
        word = keepw[w];
        const int c = __popcll(word);
        if (r < c) break;
        r -= c;
      }
      for (int q = 0; q < r; ++q) word &= word - 1;
      idx = w * 64 + (__ffsll(word) - 1);
    } else {
      int r = o - totalKeep, w = 0;
      unsigned long long word = 0ULL;
      for (; w < NW; ++w) {
        const unsigned long long mk = (w == NW - 1) ? ((1ULL << (T_CAND - 64 * (NW - 1))) - 1ULL)
                                                    : ~0ULL;
        word = (~keepw[w]) & mk;
        const int c = __popcll(word);
        if (r < c) break;
        r -= c;
      }
      for (int q = 0; q < r; ++q) word &= word - 1;
      idx = w * 64 + (__ffsll(word) - 1);
    }
    const float* pp = sPoly + (size_t)(b * T_CAND + idx) * 8;
    float* ob2 = out + (size_t)b * 800 + (size_t)o * 8;
#pragma unroll
    for (int c = 0; c < 8; ++c) ob2[c] = pp[c];
    out[1600 + b * 100 + o] = kept ? sSc[b * T_CAND + idx] : 0.0f;  // where(ok, top_s, 0)
    out[1800 + b * 100 + o] = 1.0f;                                 // labels always 1 (C=1)
    out[2000 + b * 100 + o] = kept ? 1.0f : 0.0f;                   // ok
  }
}

extern "C" void kernel_launch(void* const* d_in, const int* in_sizes, int n_in,
                              void* d_out, int out_size, void* d_ws, size_t ws_size,
                              hipStream_t stream) {
  (void)n_in; (void)out_size; (void)ws_size;
  LevelPtrs P;
  // setup_inputs() dict order is interleaved per level; detect defensively via sizes.
  const bool interleaved = (in_sizes[2] == 204800);
  for (int l = 0; l < 5; ++l) {
    if (interleaved) {
      P.loc[l] = (const float*)d_in[4 * l + 0];
      P.cls[l] = (const float*)d_in[4 * l + 1];
      P.reg[l] = (const float*)d_in[4 * l + 2];
    } else {
      P.loc[l] = (const float*)d_in[l];
      P.cls[l] = (const float*)d_in[5 + l];
      P.reg[l] = (const float*)d_in[10 + l];
    }
  }
  P.img = (const int*)d_in[20];

  char* ws = (char*)d_ws;
  float*    candPoly  = (float*)(ws + 0);          // 2*856*8*4 = 54784
  float*    candSc    = (float*)(ws + 54784);      // 6848
  unsigned* candValid = (unsigned*)(ws + 61632);   // 6848
  float*    sPoly     = (float*)(ws + 68480);      // 54784
  float*    sSc       = (float*)(ws + 123264);     // 6848
  unsigned* sValid    = (unsigned*)(ws + 130112);  // 6848
  unsigned long long* M = (unsigned long long*)(ws + 136960); // 2*856*14*8 = 191744

  topk_kernel<<<dim3(10), dim3(1024), 0, stream>>>(P, candPoly, candSc, candValid);
  sort_kernel<<<dim3(2), dim3(1024), 0, stream>>>(candPoly, candSc, candValid, sPoly, sSc, sValid);
  iou_kernel<<<dim3(7, T_CAND, 2), dim3(BSC), 0, stream>>>(sPoly, sValid, M);
  nms_out_kernel<<<dim3(2), dim3(64), 0, stream>>>(M, sPoly, sSc, sValid, (float*)d_out);
}

// Round 2
// 141.083 us; speedup vs baseline: 2.7432x; 2.7432x over previous
//
#include <hip/hip_runtime.h>

#pragma clang fp contract(off)

#define T_CAND 856
#define NW 14          // ceil(856/64)
#define BSC 128        // iou kernel block
#define NSH 16         // sub-histograms (split by (tid>>2)&15 to cut same-address atomics)
#define HSTR 513       // sub-hist stride in words (odd -> banks spread)

__device__ const int d_HW[5]  = {12800, 3200, 800, 208, 56};
__device__ const int d_K[5]   = {200, 200, 200, 200, 56};
__device__ const int d_OFF[5] = {0, 200, 400, 600, 800};

struct LevelPtrs {
  const float* loc[5];
  const float* cls[5];
  const float* reg[5];
  const int*   img;
};

// ---------------- Kernel 1: per (batch,level) stable top-K + decode ----------------
// Histogram radix-select over score-bits buckets, gather candidates >= cutoff bucket,
// then exact rank-by-counting of unique 64-bit keys (score_bits<<32 | ~idx).
// Rank-by-count of unique keys == stable descending sort permutation (validated R1).
__global__ __launch_bounds__(1024) void topk_kernel(LevelPtrs P,
    float* __restrict__ candPoly, float* __restrict__ candSc, unsigned* __restrict__ candValid) {
  __shared__ unsigned hist[NSH * HSTR];      // ~32.8 KB
  __shared__ unsigned histT[512];
  __shared__ unsigned long long gbuf[1024];  // 8 KB
  __shared__ int gcount;
  __shared__ int cutB;
  const int blk = blockIdx.x;
  const int b = blk / 5, l = blk % 5;
  const int HW = d_HW[l], K = d_K[l], OFF = d_OFF[l];
  const float* cls = P.cls[l] + (size_t)b * HW;
  const float* reg = P.reg[l] + (size_t)b * 8 * HW;
  const float* loc = P.loc[l];
  const int tid = threadIdx.x;

  for (int t = tid; t < NSH * HSTR; t += 1024) hist[t] = 0u;
  if (tid == 0) gcount = 0;
  __syncthreads();

  // pass 1: histogram of masked-score high bits (bucket = bits[31:21], max 0x1FC)
  const int sh = (tid >> 2) & (NSH - 1);
  for (int idx = tid; idx < HW; idx += 1024) {
    const float x = cls[idx];
    // correctly-rounded f32 sigmoid via double (bit-matched XLA in R1 — do not change)
    const float s = (float)(1.0 / (1.0 + exp(-(double)x)));
    const float m = (s > 0.05f) ? s : 0.0f;
    atomicAdd(&hist[sh * HSTR + (__float_as_uint(m) >> 21)], 1u);
  }
  __syncthreads();
  for (int t = tid; t < 512; t += 1024) {
    unsigned sum = 0;
#pragma unroll
    for (int h = 0; h < NSH; ++h) sum += hist[h * HSTR + t];
    histT[t] = sum;
  }
  __syncthreads();
  if (tid == 0) {
    int acc = 0, bx = 511;
    for (; bx >= 0; --bx) { acc += (int)histT[bx]; if (acc >= K) break; }
    cutB = (bx < 0) ? 0 : bx;   // total count == HW >= K, so break always fires
  }
  __syncthreads();

  // pass 2: gather all elements in buckets >= cutB (expect ~K..~2.5K of them, <= 1024)
  const int cb = cutB;
  for (int idx = tid; idx < HW; idx += 1024) {
    const float x = cls[idx];
    const float s = (float)(1.0 / (1.0 + exp(-(double)x)));
    const float m = (s > 0.05f) ? s : 0.0f;
    const unsigned kb = __float_as_uint(m);
    if ((int)(kb >> 21) >= cb) {
      const int pos = atomicAdd(&gcount, 1);
      if (pos < 1024)
        gbuf[pos] = ((unsigned long long)kb << 32)
                  | (unsigned long long)(0xFFFFFFFFu - (unsigned)idx); // tie -> lower idx first
    }
  }
  __syncthreads();

  // rank-by-count + decode
  const int G = min(gcount, 1024);
  if (tid < G) {
    const unsigned long long my = gbuf[tid];
    int rank = 0;
    for (int j = 0; j < G; ++j) rank += (gbuf[j] > my) ? 1 : 0;   // LDS broadcast reads
    if (rank < K) {
      const float val = __uint_as_float((unsigned)(my >> 32));
      const int idx = (int)(0xFFFFFFFFu - (unsigned)(my & 0xFFFFFFFFULL));
      const float hh = (float)P.img[b * 2 + 0];
      const float ww = (float)P.img[b * 2 + 1];
      const float xmax = ww - 1.0f, ymax = hh - 1.0f;
      const float lx = loc[idx * 2 + 0], ly = loc[idx * 2 + 1];
      const int go = b * T_CAND + OFF + rank;
#pragma unroll
      for (int q = 0; q < 4; ++q) {
        const float rx = reg[(2 * q + 0) * HW + idx];
        const float ry = reg[(2 * q + 1) * HW + idx];
        const float pxv = fminf(fmaxf(lx - rx, 0.0f), xmax);
        const float pyv = fminf(fmaxf(ly - ry, 0.0f), ymax);
        candPoly[go * 8 + 2 * q + 0] = pxv;
        candPoly[go * 8 + 2 * q + 1] = pyv;
      }
      const bool v = (val > 0.05f);   // bw/bh >= MIN_SIZE(0) always true after clip
      candSc[go]    = v ? sqrtf(val) : 0.0f;
      candValid[go] = v ? 1u : 0u;
    }
  }
}

// ---------------- Kernel 2: per-batch stable descending sort of 856 candidates -----
// rank-by-count of unique keys == exact stable sort permutation.
__global__ __launch_bounds__(1024) void sort_kernel(
    const float* __restrict__ candPoly, const float* __restrict__ candSc,
    const unsigned* __restrict__ candValid,
    float* __restrict__ sPoly, float* __restrict__ sSc, unsigned* __restrict__ sValid) {
  __shared__ unsigned long long key[T_CAND];
  const int b = blockIdx.x, tid = threadIdx.x;
  float sc = 0.0f;
  if (tid < T_CAND) {
    sc = candSc[b * T_CAND + tid];
    key[tid] = ((unsigned long long)__float_as_uint(sc) << 32)
             | (unsigned long long)(0xFFFFFFFFu - (unsigned)tid);
  }
  __syncthreads();
  if (tid < T_CAND) {
    const unsigned long long my = key[tid];
    int rank = 0;
    for (int j = 0; j < T_CAND; ++j) rank += (key[j] > my) ? 1 : 0;
    sSc[b * T_CAND + rank]    = sc;
    sValid[b * T_CAND + rank] = candValid[b * T_CAND + tid];
#pragma unroll
    for (int q = 0; q < 8; ++q)
      sPoly[(size_t)(b * T_CAND + rank) * 8 + q] = candPoly[(size_t)(b * T_CAND + tid) * 8 + q];
  }
}

// ---------------- Kernel 3: suppression bit-matrix via polygon-clip IoU ------------
// M[(b*T+i)*NW + jw] bit j: IoU(clip A=q[i] by B=q[j]) > 0.5, only for j>i, both valid.
__global__ __launch_bounds__(BSC) void iou_kernel(const float* __restrict__ sPoly,
                                                  const unsigned* __restrict__ sValid,
                                                  unsigned long long* __restrict__ M) {
  __shared__ float VX[2][8][BSC];
  __shared__ float VY[2][8][BSC];
  const int i = blockIdx.y, b = blockIdx.z;
  if (sValid[b * T_CAND + i] == 0u) return;   // row never applied in NMS; skip (uniform)
  const int tid = threadIdx.x;
  const int j = blockIdx.x * BSC + tid;
  const float* Ap = sPoly + (size_t)(b * T_CAND + i) * 8;
  const float ax0 = Ap[0], ay0 = Ap[1], ax1 = Ap[2], ay1 = Ap[3],
              ax2 = Ap[4], ay2 = Ap[5], ax3 = Ap[6], ay3 = Ap[7];
  const int jc = (j < T_CAND) ? j : (T_CAND - 1);
  const float* Bp = sPoly + (size_t)(b * T_CAND + jc) * 8;
  const float bx0 = Bp[0], by0 = Bp[1], bx1 = Bp[2], by1 = Bp[3],
              bx2 = Bp[4], by2 = Bp[5], bx3 = Bp[6], by3 = Bp[7];
  const bool need = (j > i) && (j < T_CAND) && (sValid[b * T_CAND + jc] != 0u);
  bool hit = false;
  if (need) {
    // signed 2*area of B (same term order as reference) -> orientation
    float sB = bx0 * by1 - bx1 * by0;
    sB += bx1 * by2 - bx2 * by1;
    sB += bx2 * by3 - bx3 * by2;
    sB += bx3 * by0 - bx0 * by3;
    const float orient = (sB >= 0.0f) ? 1.0f : -1.0f;

    VX[0][0][tid] = ax0; VY[0][0][tid] = ay0;
    VX[0][1][tid] = ax1; VY[0][1][tid] = ay1;
    VX[0][2][tid] = ax2; VY[0][2][tid] = ay2;
    VX[0][3][tid] = ax3; VY[0][3][tid] = ay3;
    int n = 4;
    const float bex[5] = {bx0, bx1, bx2, bx3, bx0};
    const float bey[5] = {by0, by1, by2, by3, by0};
#pragma unroll
    for (int e = 0; e < 4; ++e) {
      const int src = e & 1, dst = src ^ 1;
      const float p1x = bex[e], p1y = bey[e];
      const float dx = bex[e + 1] - p1x, dy = bey[e + 1] - p1y;
      int cnt = 0;
      int pidx = n - 1;                       // JAX gather clamps (incl. -1 -> 0)
      pidx = pidx < 0 ? 0 : (pidx > 7 ? 7 : pidx);
      float px = VX[src][pidx][tid], py = VY[src][pidx][tid];
      float sp = orient * (dx * (py - p1y) - dy * (px - p1x));
#pragma unroll
      for (int k = 0; k < 8; ++k) {
        const float cx = VX[src][k][tid], cy = VY[src][k][tid];
        const float sc2 = orient * (dx * (cy - p1y) - dy * (cx - p1x));
        const bool cin = (sc2 >= 0.0f), pin = (sp >= 0.0f);
        const float denom = sp - sc2;
        const float dd = (fabsf(denom) > 1e-9f) ? denom : 1e-9f;
        const float t = sp / dd;
        const float ipx = px + t * (cx - px);
        const float ipy = py + t * (cy - py);
        const bool vk = (k < n);
        const bool e1 = vk && (cin != pin);
        if (e1 && cnt < 8) { VX[dst][cnt][tid] = ipx; VY[dst][cnt][tid] = ipy; }
        cnt += e1 ? 1 : 0;                     // cnt may pass 8: writes dropped (mode='drop')
        const bool e2 = vk && cin;
        if (e2 && cnt < 8) { VX[dst][cnt][tid] = cx; VY[dst][cnt][tid] = cy; }
        cnt += e2 ? 1 : 0;
        px = cx; py = cy; sp = sc2;            // prev == V[k-1]; identical value reuse
      }
      n = cnt;
    }
    // shoelace on final buffer (buf 0 after 4 ping-pongs)
    float a = 0.0f;
#pragma unroll
    for (int k = 0; k < 8; ++k) {
      int nxt = (k == n - 1) ? 0 : ((k + 1 > 7) ? 7 : (k + 1));  // clamp like JAX
      const float xk = VX[0][k][tid], yk = VY[0][k][tid];
      const float xn = VX[0][nxt][tid], yn = VY[0][nxt][tid];
      const float term = xk * yn - xn * yk;
      a += (k < n) ? term : 0.0f;
    }
    const float inter = 0.5f * fabsf(a);
    float aA = ax0 * ay1 - ax1 * ay0;
    aA += ax1 * ay2 - ax2 * ay1;
    aA += ax2 * ay3 - ax3 * ay2;
    aA += ax3 * ay0 - ax0 * ay3;
    const float areaA = 0.5f * fabsf(aA);
    const float areaB = 0.5f * fabsf(sB);
    const float uni = areaA + areaB - inter;
    const float iou = inter / fmaxf(uni, 1e-9f);
    hit = iou > 0.5f;
  }
  const unsigned long long ball = __ballot(hit);
  if ((tid & 63) == 0) {
    const int jw = blockIdx.x * (BSC / 64) + (tid >> 6);
    M[(size_t)(b * T_CAND + i) * NW + jw] = ball;
  }
}

// ---------------- Kernel 4: serial greedy NMS (1 wave/batch) + top-100 emit --------
__global__ __launch_bounds__(64) void nms_out_kernel(const unsigned long long* __restrict__ M,
    const float* __restrict__ sPoly, const float* __restrict__ sSc,
    const unsigned* __restrict__ sValid, float* __restrict__ out) {
  const int b = blockIdx.x, lane = threadIdx.x;
  // init keep words from valid flags
  unsigned long long wk = 0ULL;
  for (int w = 0; w < NW; ++w) {
    const int idx = w * 64 + lane;
    const bool v = (idx < T_CAND) && (sValid[b * T_CAND + idx] != 0u);
    const unsigned long long ball = __ballot(v);
    if (lane == w) wk = ball;
  }
  const unsigned long long* Mb = M + (size_t)b * T_CAND * NW;
  const bool ml = lane < NW;
  unsigned long long m[8];
#pragma unroll
  for (int r = 0; r < 8; ++r) m[r] = ml ? Mb[r * NW + lane] : 0ULL;
  for (int g = 0; g < T_CAND; g += 8) {
    unsigned long long nx[8];
    const int g2 = g + 8;
#pragma unroll
    for (int r = 0; r < 8; ++r) nx[r] = (ml && g2 < T_CAND) ? Mb[(size_t)(g2 + r) * NW + lane] : 0ULL;
#pragma unroll
    for (int r = 0; r < 8; ++r) {
      const int i = g + r;
      const int ow = i >> 6, ob = i & 63;
      const unsigned rl = (unsigned)__builtin_amdgcn_readlane((int)(unsigned)(wk & 0xFFFFFFFFULL), ow);
      const unsigned rh = (unsigned)__builtin_amdgcn_readlane((int)(unsigned)(wk >> 32), ow);
      const unsigned bit = (ob < 32) ? ((rl >> ob) & 1u) : ((rh >> (ob - 32)) & 1u);
      wk &= ~(bit ? m[r] : 0ULL);
    }
#pragma unroll
    for (int r = 0; r < 8; ++r) m[r] = nx[r];
  }
  __shared__ unsigned long long keepw[NW];
  if (lane < NW) keepw[lane] = wk;
  __syncthreads();
  int totalKeep = 0;
  for (int w = 0; w < NW; ++w) totalKeep += __popcll(keepw[w]);

  for (int o = lane; o < 100; o += 64) {
    const bool kept = o < totalKeep;
    int idx = 0;
    if (kept) {
      int r = o, w = 0;
      unsigned long long word = 0ULL;
      for (; w < NW; ++w) {
        word = keepw[w];
        const int c = __popcll(word);
        if (r < c) break;
        r -= c;
      }
      for (int q = 0; q < r; ++q) word &= word - 1;
      idx = w * 64 + (__ffsll(word) - 1);
    } else {
      int r = o - totalKeep, w = 0;
      unsigned long long word = 0ULL;
      for (; w < NW; ++w) {
        const unsigned long long mk = (w == NW - 1) ? ((1ULL << (T_CAND - 64 * (NW - 1))) - 1ULL)
                                                    : ~0ULL;
        word = (~keepw[w]) & mk;
        const int c = __popcll(word);
        if (r < c) break;
        r -= c;
      }
      for (int q = 0; q < r; ++q) word &= word - 1;
      idx = w * 64 + (__ffsll(word) - 1);
    }
    const float* pp = sPoly + (size_t)(b * T_CAND + idx) * 8;
    float* ob2 = out + (size_t)b * 800 + (size_t)o * 8;
#pragma unroll
    for (int c = 0; c < 8; ++c) ob2[c] = pp[c];
    out[1600 + b * 100 + o] = kept ? sSc[b * T_CAND + idx] : 0.0f;  // where(ok, top_s, 0)
    out[1800 + b * 100 + o] = 1.0f;                                 // labels always 1 (C=1)
    out[2000 + b * 100 + o] = kept ? 1.0f : 0.0f;                   // ok
  }
}

extern "C" void kernel_launch(void* const* d_in, const int* in_sizes, int n_in,
                              void* d_out, int out_size, void* d_ws, size_t ws_size,
                              hipStream_t stream) {
  (void)n_in; (void)out_size; (void)ws_size;
  LevelPtrs P;
  // setup_inputs() dict order is interleaved per level; detect defensively via sizes.
  const bool interleaved = (in_sizes[2] == 204800);
  for (int l = 0; l < 5; ++l) {
    if (interleaved) {
      P.loc[l] = (const float*)d_in[4 * l + 0];
      P.cls[l] = (const float*)d_in[4 * l + 1];
      P.reg[l] = (const float*)d_in[4 * l + 2];
    } else {
      P.loc[l] = (const float*)d_in[l];
      P.cls[l] = (const float*)d_in[5 + l];
      P.reg[l] = (const float*)d_in[10 + l];
    }
  }
  P.img = (const int*)d_in[20];

  char* ws = (char*)d_ws;
  float*    candPoly  = (float*)(ws + 0);          // 2*856*8*4 = 54784
  float*    candSc    = (float*)(ws + 54784);      // 6848
  unsigned* candValid = (unsigned*)(ws + 61632);   // 6848
  float*    sPoly     = (float*)(ws + 68480);      // 54784
  float*    sSc       = (float*)(ws + 123264);     // 6848
  unsigned* sValid    = (unsigned*)(ws + 130112);  // 6848
  unsigned long long* M = (unsigned long long*)(ws + 136960); // 2*856*14*8 = 191744

  topk_kernel<<<dim3(10), dim3(1024), 0, stream>>>(P, candPoly, candSc, candValid);
  sort_kernel<<<dim3(2), dim3(1024), 0, stream>>>(candPoly, candSc, candValid, sPoly, sSc, sValid);
  iou_kernel<<<dim3(7, T_CAND, 2), dim3(BSC), 0, stream>>>(sPoly, sValid, M);
  nms_out_kernel<<<dim3(2), dim3(64), 0, stream>>>(M, sPoly, sSc, sValid, (float*)d_out);
}

// Round 3
// 140.831 us; speedup vs baseline: 2.7481x; 1.0018x over previous
//
#include <hip/hip_runtime.h>

#pragma clang fp contract(off)

#define T_CAND 856
#define NW 14          // ceil(856/64)
#define BSC 128        // iou kernel block
#define NSH 16         // sub-histograms (split by (tid>>2)&15 to cut same-address atomics)
#define HSTR 513       // sub-hist stride in words (odd -> banks spread)

__device__ const int d_HW[5]  = {12800, 3200, 800, 208, 56};
__device__ const int d_K[5]   = {200, 200, 200, 200, 56};
__device__ const int d_OFF[5] = {0, 200, 400, 600, 800};

struct LevelPtrs {
  const float* loc[5];
  const float* cls[5];
  const float* reg[5];
  const int*   img;
};

__device__ __forceinline__ unsigned long long readlane64(unsigned long long v, int lane) {
  const unsigned lo = (unsigned)__builtin_amdgcn_readlane((int)(unsigned)(v & 0xFFFFFFFFULL), lane);
  const unsigned hi = (unsigned)__builtin_amdgcn_readlane((int)(unsigned)(v >> 32), lane);
  return ((unsigned long long)hi << 32) | lo;
}

// ---------------- Kernel 1: per (batch,level) stable top-K + decode ----------------
// Histogram radix-select over score-bits buckets, gather candidates >= cutoff bucket,
// then exact rank-by-counting of unique 64-bit keys (score_bits<<32 | ~idx).
// Rank-by-count of unique keys == stable descending sort permutation (validated R1/R2).
__global__ __launch_bounds__(1024) void topk_kernel(LevelPtrs P,
    float* __restrict__ candPoly, float* __restrict__ candSc, unsigned* __restrict__ candValid) {
  __shared__ unsigned hist[NSH * HSTR];      // ~32.8 KB
  __shared__ unsigned histT[512];
  __shared__ __align__(16) unsigned long long gbuf[1024];  // 8 KB
  __shared__ int gcount;
  __shared__ int cutB;
  const int blk = blockIdx.x;
  const int b = blk / 5, l = blk % 5;
  const int HW = d_HW[l], K = d_K[l], OFF = d_OFF[l];
  const float* cls = P.cls[l] + (size_t)b * HW;
  const float* reg = P.reg[l] + (size_t)b * 8 * HW;
  const float* loc = P.loc[l];
  const int tid = threadIdx.x;

  for (int t = tid; t < NSH * HSTR; t += 1024) hist[t] = 0u;
  if (tid == 0) gcount = 0;
  __syncthreads();

  // pass 1: histogram of masked-score high bits (bucket = bits[31:21], max 0x1FC)
  const int sh = (tid >> 2) & (NSH - 1);
  for (int idx = tid; idx < HW; idx += 1024) {
    const float x = cls[idx];
    // correctly-rounded f32 sigmoid via double (bit-matched XLA in R1 — do not change)
    const float s = (float)(1.0 / (1.0 + exp(-(double)x)));
    const float m = (s > 0.05f) ? s : 0.0f;
    atomicAdd(&hist[sh * HSTR + (__float_as_uint(m) >> 21)], 1u);
  }
  __syncthreads();
  for (int t = tid; t < 512; t += 1024) {
    unsigned sum = 0;
#pragma unroll
    for (int h = 0; h < NSH; ++h) sum += hist[h * HSTR + t];
    histT[t] = sum;
  }
  __syncthreads();
  if (tid == 0) {
    int acc = 0, bx = 511;
    for (; bx >= 0; --bx) { acc += (int)histT[bx]; if (acc >= K) break; }
    cutB = (bx < 0) ? 0 : bx;   // total count == HW >= K, so break always fires
  }
  __syncthreads();

  // pass 2: gather all elements in buckets >= cutB (expect ~K..~2.5K of them, <= 1024)
  const int cb = cutB;
  for (int idx = tid; idx < HW; idx += 1024) {
    const float x = cls[idx];
    const float s = (float)(1.0 / (1.0 + exp(-(double)x)));
    const float m = (s > 0.05f) ? s : 0.0f;
    const unsigned kb = __float_as_uint(m);
    if ((int)(kb >> 21) >= cb) {
      const int pos = atomicAdd(&gcount, 1);
      if (pos < 1024)
        gbuf[pos] = ((unsigned long long)kb << 32)
                  | (unsigned long long)(0xFFFFFFFFu - (unsigned)idx); // tie -> lower idx first
    }
  }
  __syncthreads();
  const int G = min(gcount, 1024);
  if (tid < 4 && G + tid < 1024) gbuf[G + tid] = 0ULL;   // pad so vector loop reads zeros
  __syncthreads();

  // rank-by-count + decode (vectorized LDS reads; pad keys 0 never count: any real key > 0)
  if (tid < G) {
    const unsigned long long my = gbuf[tid];
    const int G4 = (G + 3) & ~3;
    int rank = 0;
    const ulonglong2* g2 = (const ulonglong2*)gbuf;
    for (int j = 0; j < G4 / 2; j += 2) {
      const ulonglong2 a = g2[j], c = g2[j + 1];
      rank += (a.x > my) ? 1 : 0;
      rank += (a.y > my) ? 1 : 0;
      rank += (c.x > my) ? 1 : 0;
      rank += (c.y > my) ? 1 : 0;
    }
    if (rank < K) {
      const float val = __uint_as_float((unsigned)(my >> 32));
      const int idx = (int)(0xFFFFFFFFu - (unsigned)(my & 0xFFFFFFFFULL));
      const float hh = (float)P.img[b * 2 + 0];
      const float ww = (float)P.img[b * 2 + 1];
      const float xmax = ww - 1.0f, ymax = hh - 1.0f;
      const float lx = loc[idx * 2 + 0], ly = loc[idx * 2 + 1];
      const int go = b * T_CAND + OFF + rank;
#pragma unroll
      for (int q = 0; q < 4; ++q) {
        const float rx = reg[(2 * q + 0) * HW + idx];
        const float ry = reg[(2 * q + 1) * HW + idx];
        const float pxv = fminf(fmaxf(lx - rx, 0.0f), xmax);
        const float pyv = fminf(fmaxf(ly - ry, 0.0f), ymax);
        candPoly[go * 8 + 2 * q + 0] = pxv;
        candPoly[go * 8 + 2 * q + 1] = pyv;
      }
      const bool v = (val > 0.05f);   // bw/bh >= MIN_SIZE(0) always true after clip
      candSc[go]    = v ? sqrtf(val) : 0.0f;
      candValid[go] = v ? 1u : 0u;
    }
  }
}

// ---------------- Kernel 2: per-batch stable descending sort of 856 candidates -----
// rank-by-count of unique keys == exact stable sort permutation.
__global__ __launch_bounds__(1024) void sort_kernel(
    const float* __restrict__ candPoly, const float* __restrict__ candSc,
    const unsigned* __restrict__ candValid,
    float* __restrict__ sPoly, float* __restrict__ sSc, unsigned* __restrict__ sValid) {
  __shared__ __align__(16) unsigned long long key[T_CAND];
  const int b = blockIdx.x, tid = threadIdx.x;
  float sc = 0.0f;
  if (tid < T_CAND) {
    sc = candSc[b * T_CAND + tid];
    key[tid] = ((unsigned long long)__float_as_uint(sc) << 32)
             | (unsigned long long)(0xFFFFFFFFu - (unsigned)tid);
  }
  __syncthreads();
  if (tid < T_CAND) {
    const unsigned long long my = key[tid];
    int rank = 0;
    const ulonglong2* k2 = (const ulonglong2*)key;
    for (int j = 0; j < T_CAND / 2; j += 2) {   // 856/4 = 214 iters, 2x ds_read_b128
      const ulonglong2 a = k2[j], c = k2[j + 1];
      rank += (a.x > my) ? 1 : 0;
      rank += (a.y > my) ? 1 : 0;
      rank += (c.x > my) ? 1 : 0;
      rank += (c.y > my) ? 1 : 0;
    }
    sSc[b * T_CAND + rank]    = sc;
    sValid[b * T_CAND + rank] = candValid[b * T_CAND + tid];
#pragma unroll
    for (int q = 0; q < 8; ++q)
      sPoly[(size_t)(b * T_CAND + rank) * 8 + q] = candPoly[(size_t)(b * T_CAND + tid) * 8 + q];
  }
}

// ---------------- Kernel 3: suppression bit-matrix via polygon-clip IoU ------------
// M[(b*T+i)*NW + jw] bit j: IoU(clip A=q[i] by B=q[j]) > 0.5, only for j>i, both valid.
__global__ __launch_bounds__(BSC) void iou_kernel(const float* __restrict__ sPoly,
                                                  const unsigned* __restrict__ sValid,
                                                  unsigned long long* __restrict__ M) {
  __shared__ float VX[2][8][BSC];
  __shared__ float VY[2][8][BSC];
  const int i = blockIdx.y, b = blockIdx.z;
  if (sValid[b * T_CAND + i] == 0u) return;   // row never applied in NMS; skip (uniform)
  const int tid = threadIdx.x;
  const int j = blockIdx.x * BSC + tid;
  const float* Ap = sPoly + (size_t)(b * T_CAND + i) * 8;
  const float ax0 = Ap[0], ay0 = Ap[1], ax1 = Ap[2], ay1 = Ap[3],
              ax2 = Ap[4], ay2 = Ap[5], ax3 = Ap[6], ay3 = Ap[7];
  const int jc = (j < T_CAND) ? j : (T_CAND - 1);
  const float* Bp = sPoly + (size_t)(b * T_CAND + jc) * 8;
  const float bx0 = Bp[0], by0 = Bp[1], bx1 = Bp[2], by1 = Bp[3],
              bx2 = Bp[4], by2 = Bp[5], bx3 = Bp[6], by3 = Bp[7];
  const bool need = (j > i) && (j < T_CAND) && (sValid[b * T_CAND + jc] != 0u);
  // AABB quick-reject: disjoint AABBs => intersection polygon empty => inter == 0 exactly
  // => iou == 0 => hit false, bit-identical to running the clip. Touching AABBs run full path.
  const float aminx = fminf(fminf(ax0, ax1), fminf(ax2, ax3));
  const float amaxx = fmaxf(fmaxf(ax0, ax1), fmaxf(ax2, ax3));
  const float aminy = fminf(fminf(ay0, ay1), fminf(ay2, ay3));
  const float amaxy = fmaxf(fmaxf(ay0, ay1), fmaxf(ay2, ay3));
  const float bminx = fminf(fminf(bx0, bx1), fminf(bx2, bx3));
  const float bmaxx = fmaxf(fmaxf(bx0, bx1), fmaxf(bx2, bx3));
  const float bminy = fminf(fminf(by0, by1), fminf(by2, by3));
  const float bmaxy = fmaxf(fmaxf(by0, by1), fmaxf(by2, by3));
  const bool ov = !(amaxx < bminx || bmaxx < aminx || amaxy < bminy || bmaxy < aminy);
  bool hit = false;
  if (need && ov) {
    // signed 2*area of B (same term order as reference) -> orientation
    float sB = bx0 * by1 - bx1 * by0;
    sB += bx1 * by2 - bx2 * by1;
    sB += bx2 * by3 - bx3 * by2;
    sB += bx3 * by0 - bx0 * by3;
    const float orient = (sB >= 0.0f) ? 1.0f : -1.0f;

    VX[0][0][tid] = ax0; VY[0][0][tid] = ay0;
    VX[0][1][tid] = ax1; VY[0][1][tid] = ay1;
    VX[0][2][tid] = ax2; VY[0][2][tid] = ay2;
    VX[0][3][tid] = ax3; VY[0][3][tid] = ay3;
    int n = 4;
    const float bex[5] = {bx0, bx1, bx2, bx3, bx0};
    const float bey[5] = {by0, by1, by2, by3, by0};
#pragma unroll
    for (int e = 0; e < 4; ++e) {
      const int src = e & 1, dst = src ^ 1;
      const float p1x = bex[e], p1y = bey[e];
      const float dx = bex[e + 1] - p1x, dy = bey[e + 1] - p1y;
      int cnt = 0;
      int pidx = n - 1;                       // JAX gather clamps (incl. -1 -> 0)
      pidx = pidx < 0 ? 0 : (pidx > 7 ? 7 : pidx);
      float px = VX[src][pidx][tid], py = VY[src][pidx][tid];
      float sp = orient * (dx * (py - p1y) - dy * (px - p1x));
#pragma unroll
      for (int k = 0; k < 8; ++k) {
        const float cx = VX[src][k][tid], cy = VY[src][k][tid];
        const float sc2 = orient * (dx * (cy - p1y) - dy * (cx - p1x));
        const bool cin = (sc2 >= 0.0f), pin = (sp >= 0.0f);
        const float denom = sp - sc2;
        const float dd = (fabsf(denom) > 1e-9f) ? denom : 1e-9f;
        const float t = sp / dd;
        const float ipx = px + t * (cx - px);
        const float ipy = py + t * (cy - py);
        const bool vk = (k < n);
        const bool e1 = vk && (cin != pin);
        if (e1 && cnt < 8) { VX[dst][cnt][tid] = ipx; VY[dst][cnt][tid] = ipy; }
        cnt += e1 ? 1 : 0;                     // cnt may pass 8: writes dropped (mode='drop')
        const bool e2 = vk && cin;
        if (e2 && cnt < 8) { VX[dst][cnt][tid] = cx; VY[dst][cnt][tid] = cy; }
        cnt += e2 ? 1 : 0;
        px = cx; py = cy; sp = sc2;            // prev == V[k-1]; identical value reuse
      }
      n = cnt;
    }
    // shoelace on final buffer (buf 0 after 4 ping-pongs)
    float a = 0.0f;
#pragma unroll
    for (int k = 0; k < 8; ++k) {
      int nxt = (k == n - 1) ? 0 : ((k + 1 > 7) ? 7 : (k + 1));  // clamp like JAX
      const float xk = VX[0][k][tid], yk = VY[0][k][tid];
      const float xn = VX[0][nxt][tid], yn = VY[0][nxt][tid];
      const float term = xk * yn - xn * yk;
      a += (k < n) ? term : 0.0f;
    }
    const float inter = 0.5f * fabsf(a);
    float aA = ax0 * ay1 - ax1 * ay0;
    aA += ax1 * ay2 - ax2 * ay1;
    aA += ax2 * ay3 - ax3 * ay2;
    aA += ax3 * ay0 - ax0 * ay3;
    const float areaA = 0.5f * fabsf(aA);
    const float areaB = 0.5f * fabsf(sB);
    const float uni = areaA + areaB - inter;
    const float iou = inter / fmaxf(uni, 1e-9f);
    hit = iou > 0.5f;
  }
  const unsigned long long ball = __ballot(hit);
  if ((tid & 63) == 0) {
    const int jw = blockIdx.x * (BSC / 64) + (tid >> 6);
    M[(size_t)(b * T_CAND + i) * NW + jw] = ball;
  }
}

// ---------------- Kernel 4: blocked greedy NMS (1 wave/batch) + top-100 emit -------
// 14 blocks of 64. Intra-block: scalar-uniform set-bit loop (chain = #survivors).
// Cross-block: lane w holds running suppression word S_w, updated by OR of kept rows
// (LDS-staged, double-buffered, global loads issued one block ahead).
__global__ __launch_bounds__(64) void nms_out_kernel(const unsigned long long* __restrict__ M,
    const float* __restrict__ sPoly, const float* __restrict__ sSc,
    const unsigned* __restrict__ sValid, float* __restrict__ out) {
  const int b = blockIdx.x, lane = threadIdx.x;
  const unsigned long long* Mb = M + (size_t)b * T_CAND * NW;
  __shared__ unsigned long long rows[2][64 * NW];   // 2 x 7 KB
  __shared__ unsigned long long keepw[NW];

  // prefetch valid flags for all 14 blocks
  unsigned vflag[NW];
#pragma unroll
  for (int q = 0; q < NW; ++q) {
    const int idx = q * 64 + lane;
    vflag[q] = (idx < T_CAND) ? sValid[b * T_CAND + idx] : 0u;
  }
  // prefetch block 0 rows (linear block layout == row-major [row][word])
  unsigned long long pre[NW];
#pragma unroll
  for (int k = 0; k < NW; ++k) pre[k] = Mb[k * 64 + lane];
#pragma unroll
  for (int k = 0; k < NW; ++k) rows[0][k * 64 + lane] = pre[k];
  __syncthreads();

  unsigned long long S = 0ULL;   // lane w (w<NW): suppression word w from previous blocks
#pragma unroll
  for (int q = 0; q < NW; ++q) {
    const int cur = q & 1;
    // issue next-block prefetch (consumed after resolve: HBM/L3 latency hidden)
    if (q < NW - 1) {
#pragma unroll
      for (int k = 0; k < NW; ++k) {
        int ofs = (q + 1) * 64 * NW + k * 64 + lane;
        ofs = (ofs < T_CAND * NW) ? ofs : (T_CAND * NW - 1);  // partial last block: pad reads
        pre[k] = Mb[ofs];
      }
    }
    // initial keep = valid & ~cross-block suppression
    unsigned long long keep = __ballot(vflag[q] != 0u);
    keep &= ~readlane64(S, q);
    // intra-block suppression column: lane s's row, word q (static q: loop unrolled)
    const unsigned long long sup = rows[cur][lane * NW + q];
    // serial greedy over surviving set bits only
    unsigned long long alive = keep, rem = keep;
    while (rem) {
      const int s = (int)__builtin_ctzll(rem);
      alive &= ~readlane64(sup, s);
      rem = (rem & (rem - 1)) & alive;
    }
    if (lane == 0) keepw[q] = alive;
    // fold kept rows into S (pipelined ds_read_b64 + OR; no dependency chain).
    // Row bits in words < q are zero by construction (M has only j>i bits), so OR-ing
    // the whole row is safe. Lanes >= NW read in-bounds garbage into unused S.
    unsigned long long t = alive;
    while (t) {
      const int i = (int)__builtin_ctzll(t);
      t &= t - 1;
      S |= rows[cur][i * NW + lane];
    }
    // stage next block into the other buffer
    if (q < NW - 1) {
#pragma unroll
      for (int k = 0; k < NW; ++k) rows[cur ^ 1][k * 64 + lane] = pre[k];
    }
    __syncthreads();
  }

  int totalKeep = 0;
  for (int w = 0; w < NW; ++w) totalKeep += __popcll(keepw[w]);

  for (int o = lane; o < 100; o += 64) {
    const bool kept = o < totalKeep;
    int idx = 0;
    if (kept) {
      int r = o, w = 0;
      unsigned long long word = 0ULL;
      for (; w < NW; ++w) {
        word = keepw[w];
        const int c = __popcll(word);
        if (r < c) break;
        r -= c;
      }
      for (int p = 0; p < r; ++p) word &= word - 1;
      idx = w * 64 + (__ffsll(word) - 1);
    } else {
      int r = o - totalKeep, w = 0;
      unsigned long long word = 0ULL;
      for (; w < NW; ++w) {
        const unsigned long long mk = (w == NW - 1) ? ((1ULL << (T_CAND - 64 * (NW - 1))) - 1ULL)
                                                    : ~0ULL;
        word = (~keepw[w]) & mk;
        const int c = __popcll(word);
        if (r < c) break;
        r -= c;
      }
      for (int p = 0; p < r; ++p) word &= word - 1;
      idx = w * 64 + (__ffsll(word) - 1);
    }
    const float* pp = sPoly + (size_t)(b * T_CAND + idx) * 8;
    float* ob2 = out + (size_t)b * 800 + (size_t)o * 8;
#pragma unroll
    for (int c = 0; c < 8; ++c) ob2[c] = pp[c];
    out[1600 + b * 100 + o] = kept ? sSc[b * T_CAND + idx] : 0.0f;  // where(ok, top_s, 0)
    out[1800 + b * 100 + o] = 1.0f;                                 // labels always 1 (C=1)
    out[2000 + b * 100 + o] = kept ? 1.0f : 0.0f;                   // ok
  }
}

extern "C" void kernel_launch(void* const* d_in, const int* in_sizes, int n_in,
                              void* d_out, int out_size, void* d_ws, size_t ws_size,
                              hipStream_t stream) {
  (void)n_in; (void)out_size; (void)ws_size;
  LevelPtrs P;
  // setup_inputs() dict order is interleaved per level; detect defensively via sizes.
  const bool interleaved = (in_sizes[2] == 204800);
  for (int l = 0; l < 5; ++l) {
    if (interleaved) {
      P.loc[l] = (const float*)d_in[4 * l + 0];
      P.cls[l] = (const float*)d_in[4 * l + 1];
      P.reg[l] = (const float*)d_in[4 * l + 2];
    } else {
      P.loc[l] = (const float*)d_in[l];
      P.cls[l] = (const float*)d_in[5 + l];
      P.reg[l] = (const float*)d_in[10 + l];
    }
  }
  P.img = (const int*)d_in[20];

  char* ws = (char*)d_ws;
  float*    candPoly  = (float*)(ws + 0);          // 2*856*8*4 = 54784
  float*    candSc    = (float*)(ws + 54784);      // 6848
  unsigned* candValid = (unsigned*)(ws + 61632);   // 6848
  float*    sPoly     = (float*)(ws + 68480);      // 54784
  float*    sSc       = (float*)(ws + 123264);     // 6848
  unsigned* sValid    = (unsigned*)(ws + 130112);  // 6848
  unsigned long long* M = (unsigned long long*)(ws + 136960); // 2*856*14*8 = 191744

  topk_kernel<<<dim3(10), dim3(1024), 0, stream>>>(P, candPoly, candSc, candValid);
  sort_kernel<<<dim3(2), dim3(1024), 0, stream>>>(candPoly, candSc, candValid, sPoly, sSc, sValid);
  iou_kernel<<<dim3(7, T_CAND, 2), dim3(BSC), 0, stream>>>(sPoly, sValid, M);
  nms_out_kernel<<<dim3(2), dim3(64), 0, stream>>>(M, sPoly, sSc, sValid, (float*)d_out);
}

// Round 4
// 128.232 us; speedup vs baseline: 3.0181x; 1.0983x over previous
//
#include <hip/hip_runtime.h>

#pragma clang fp contract(off)

#define T_CAND 856
#define NW 14          // ceil(856/64)
#define BSC 128        // iou kernel block
#define NSH 16         // sub-histograms (split by (tid>>2)&15 to cut same-address atomics)
#define HSTR 513       // sub-hist stride in words (odd -> banks spread)

__device__ const int d_HW[5]  = {12800, 3200, 800, 208, 56};
__device__ const int d_K[5]   = {200, 200, 200, 200, 56};
__device__ const int d_OFF[5] = {0, 200, 400, 600, 800};

struct LevelPtrs {
  const float* loc[5];
  const float* cls[5];
  const float* reg[5];
  const int*   img;
};

__device__ __forceinline__ unsigned long long readlane64(unsigned long long v, int lane) {
  const unsigned lo = (unsigned)__builtin_amdgcn_readlane((int)(unsigned)(v & 0xFFFFFFFFULL), lane);
  const unsigned hi = (unsigned)__builtin_amdgcn_readlane((int)(unsigned)(v >> 32), lane);
  return ((unsigned long long)hi << 32) | lo;
}

// ---------------- Kernel 1: per (batch,level) stable top-K + decode ----------------
// Histogram radix-select over score-bits buckets, gather candidates >= cutoff bucket,
// then exact rank-by-counting of unique 64-bit keys (score_bits<<32 | ~idx).
// Rank-by-count of unique keys == stable descending sort permutation (validated R1/R2).
__global__ __launch_bounds__(1024) void topk_kernel(LevelPtrs P,
    float* __restrict__ candPoly, float* __restrict__ candSc, unsigned* __restrict__ candValid) {
  __shared__ unsigned hist[NSH * HSTR];      // ~32.8 KB
  __shared__ unsigned histT[512];
  __shared__ __align__(16) unsigned long long gbuf[1024];  // 8 KB
  __shared__ int gcount;
  __shared__ int cutB;
  const int blk = blockIdx.x;
  const int b = blk / 5, l = blk % 5;
  const int HW = d_HW[l], K = d_K[l], OFF = d_OFF[l];
  const float* cls = P.cls[l] + (size_t)b * HW;
  const float* reg = P.reg[l] + (size_t)b * 8 * HW;
  const float* loc = P.loc[l];
  const int tid = threadIdx.x;

  for (int t = tid; t < NSH * HSTR; t += 1024) hist[t] = 0u;
  if (tid == 0) gcount = 0;
  __syncthreads();

  // pass 1: histogram of masked-score high bits (bucket = bits[31:21], max 0x1FC)
  const int sh = (tid >> 2) & (NSH - 1);
  for (int idx = tid; idx < HW; idx += 1024) {
    const float x = cls[idx];
    // correctly-rounded f32 sigmoid via double (bit-matched XLA in R1 — do not change)
    const float s = (float)(1.0 / (1.0 + exp(-(double)x)));
    const float m = (s > 0.05f) ? s : 0.0f;
    atomicAdd(&hist[sh * HSTR + (__float_as_uint(m) >> 21)], 1u);
  }
  __syncthreads();
  for (int t = tid; t < 512; t += 1024) {
    unsigned sum = 0;
#pragma unroll
    for (int h = 0; h < NSH; ++h) sum += hist[h * HSTR + t];
    histT[t] = sum;
  }
  __syncthreads();
  if (tid == 0) {
    int acc = 0, bx = 511;
    for (; bx >= 0; --bx) { acc += (int)histT[bx]; if (acc >= K) break; }
    cutB = (bx < 0) ? 0 : bx;   // total count == HW >= K, so break always fires
  }
  __syncthreads();

  // pass 2: gather all elements in buckets >= cutB (expect ~K..~2.5K of them, <= 1024)
  const int cb = cutB;
  for (int idx = tid; idx < HW; idx += 1024) {
    const float x = cls[idx];
    const float s = (float)(1.0 / (1.0 + exp(-(double)x)));
    const float m = (s > 0.05f) ? s : 0.0f;
    const unsigned kb = __float_as_uint(m);
    if ((int)(kb >> 21) >= cb) {
      const int pos = atomicAdd(&gcount, 1);
      if (pos < 1024)
        gbuf[pos] = ((unsigned long long)kb << 32)
                  | (unsigned long long)(0xFFFFFFFFu - (unsigned)idx); // tie -> lower idx first
    }
  }
  __syncthreads();
  const int G = min(gcount, 1024);
  if (tid < 4 && G + tid < 1024) gbuf[G + tid] = 0ULL;   // pad so vector loop reads zeros
  __syncthreads();

  // rank-by-count + decode (vectorized LDS reads; pad keys 0 never count: any real key > 0)
  if (tid < G) {
    const unsigned long long my = gbuf[tid];
    const int G4 = (G + 3) & ~3;
    int rank = 0;
    const ulonglong2* g2 = (const ulonglong2*)gbuf;
    for (int j = 0; j < G4 / 2; j += 2) {
      const ulonglong2 a = g2[j], c = g2[j + 1];
      rank += (a.x > my) ? 1 : 0;
      rank += (a.y > my) ? 1 : 0;
      rank += (c.x > my) ? 1 : 0;
      rank += (c.y > my) ? 1 : 0;
    }
    if (rank < K) {
      const float val = __uint_as_float((unsigned)(my >> 32));
      const int idx = (int)(0xFFFFFFFFu - (unsigned)(my & 0xFFFFFFFFULL));
      const float hh = (float)P.img[b * 2 + 0];
      const float ww = (float)P.img[b * 2 + 1];
      const float xmax = ww - 1.0f, ymax = hh - 1.0f;
      const float lx = loc[idx * 2 + 0], ly = loc[idx * 2 + 1];
      const int go = b * T_CAND + OFF + rank;
#pragma unroll
      for (int q = 0; q < 4; ++q) {
        const float rx = reg[(2 * q + 0) * HW + idx];
        const float ry = reg[(2 * q + 1) * HW + idx];
        const float pxv = fminf(fmaxf(lx - rx, 0.0f), xmax);
        const float pyv = fminf(fmaxf(ly - ry, 0.0f), ymax);
        candPoly[go * 8 + 2 * q + 0] = pxv;
        candPoly[go * 8 + 2 * q + 1] = pyv;
      }
      const bool v = (val > 0.05f);   // bw/bh >= MIN_SIZE(0) always true after clip
      candSc[go]    = v ? sqrtf(val) : 0.0f;
      candValid[go] = v ? 1u : 0u;
    }
  }
}

// ---------------- Kernel 2: per-batch stable descending sort of 856 candidates -----
// rank-by-count of unique keys == exact stable sort permutation.
__global__ __launch_bounds__(1024) void sort_kernel(
    const float* __restrict__ candPoly, const float* __restrict__ candSc,
    const unsigned* __restrict__ candValid,
    float* __restrict__ sPoly, float* __restrict__ sSc, unsigned* __restrict__ sValid) {
  __shared__ __align__(16) unsigned long long key[T_CAND];
  const int b = blockIdx.x, tid = threadIdx.x;
  float sc = 0.0f;
  if (tid < T_CAND) {
    sc = candSc[b * T_CAND + tid];
    key[tid] = ((unsigned long long)__float_as_uint(sc) << 32)
             | (unsigned long long)(0xFFFFFFFFu - (unsigned)tid);
  }
  __syncthreads();
  if (tid < T_CAND) {
    const unsigned long long my = key[tid];
    int rank = 0;
    const ulonglong2* k2 = (const ulonglong2*)key;
    for (int j = 0; j < T_CAND / 2; j += 2) {   // 856/4 = 214 iters, 2x ds_read_b128
      const ulonglong2 a = k2[j], c = k2[j + 1];
      rank += (a.x > my) ? 1 : 0;
      rank += (a.y > my) ? 1 : 0;
      rank += (c.x > my) ? 1 : 0;
      rank += (c.y > my) ? 1 : 0;
    }
    sSc[b * T_CAND + rank]    = sc;
    sValid[b * T_CAND + rank] = candValid[b * T_CAND + tid];
    const float4* src = (const float4*)(candPoly + (size_t)(b * T_CAND + tid) * 8);
    float4* dst = (float4*)(sPoly + (size_t)(b * T_CAND + rank) * 8);
    dst[0] = src[0];
    dst[1] = src[1];
  }
}

// ---------------- Kernel 3: suppression bit-matrix via polygon-clip IoU ------------
// TRANSPOSED layout: MT[(b*NW + jw)*856 + i] bit j%64: IoU(A=q[i], B=q[j]) > 0.5,
// only for j>i, both valid.
__global__ __launch_bounds__(BSC) void iou_kernel(const float* __restrict__ sPoly,
                                                  const unsigned* __restrict__ sValid,
                                                  unsigned long long* __restrict__ MT) {
  __shared__ float VX[2][8][BSC];
  __shared__ float VY[2][8][BSC];
  const int i = blockIdx.y, b = blockIdx.z;
  if (sValid[b * T_CAND + i] == 0u) return;   // row never applied in NMS; skip (uniform)
  const int tid = threadIdx.x;
  const int j = blockIdx.x * BSC + tid;
  const float4* Ap4 = (const float4*)(sPoly + (size_t)(b * T_CAND + i) * 8);
  const float4 a01 = Ap4[0], a23 = Ap4[1];
  const float ax0 = a01.x, ay0 = a01.y, ax1 = a01.z, ay1 = a01.w,
              ax2 = a23.x, ay2 = a23.y, ax3 = a23.z, ay3 = a23.w;
  const int jc = (j < T_CAND) ? j : (T_CAND - 1);
  const float4* Bp4 = (const float4*)(sPoly + (size_t)(b * T_CAND + jc) * 8);
  const float4 b01 = Bp4[0], b23 = Bp4[1];
  const float bx0 = b01.x, by0 = b01.y, bx1 = b01.z, by1 = b01.w,
              bx2 = b23.x, by2 = b23.y, bx3 = b23.z, by3 = b23.w;
  const bool need = (j > i) && (j < T_CAND) && (sValid[b * T_CAND + jc] != 0u);
  // AABB quick-reject: disjoint AABBs => intersection polygon empty => inter == 0 exactly
  // => iou == 0 => hit false, bit-identical to running the clip. Touching AABBs run full path.
  const float aminx = fminf(fminf(ax0, ax1), fminf(ax2, ax3));
  const float amaxx = fmaxf(fmaxf(ax0, ax1), fmaxf(ax2, ax3));
  const float aminy = fminf(fminf(ay0, ay1), fminf(ay2, ay3));
  const float amaxy = fmaxf(fmaxf(ay0, ay1), fmaxf(ay2, ay3));
  const float bminx = fminf(fminf(bx0, bx1), fminf(bx2, bx3));
  const float bmaxx = fmaxf(fmaxf(bx0, bx1), fmaxf(bx2, bx3));
  const float bminy = fminf(fminf(by0, by1), fminf(by2, by3));
  const float bmaxy = fmaxf(fmaxf(by0, by1), fmaxf(by2, by3));
  const bool ov = !(amaxx < bminx || bmaxx < aminx || amaxy < bminy || bmaxy < aminy);
  bool hit = false;
  if (need && ov) {
    // signed 2*area of B (same term order as reference) -> orientation
    float sB = bx0 * by1 - bx1 * by0;
    sB += bx1 * by2 - bx2 * by1;
    sB += bx2 * by3 - bx3 * by2;
    sB += bx3 * by0 - bx0 * by3;
    const float orient = (sB >= 0.0f) ? 1.0f : -1.0f;

    VX[0][0][tid] = ax0; VY[0][0][tid] = ay0;
    VX[0][1][tid] = ax1; VY[0][1][tid] = ay1;
    VX[0][2][tid] = ax2; VY[0][2][tid] = ay2;
    VX[0][3][tid] = ax3; VY[0][3][tid] = ay3;
    int n = 4;
    const float bex[5] = {bx0, bx1, bx2, bx3, bx0};
    const float bey[5] = {by0, by1, by2, by3, by0};
#pragma unroll
    for (int e = 0; e < 4; ++e) {
      const int src = e & 1, dst = src ^ 1;
      const float p1x = bex[e], p1y = bey[e];
      const float dx = bex[e + 1] - p1x, dy = bey[e + 1] - p1y;
      int cnt = 0;
      int pidx = n - 1;                       // JAX gather clamps (incl. -1 -> 0)
      pidx = pidx < 0 ? 0 : (pidx > 7 ? 7 : pidx);
      float px = VX[src][pidx][tid], py = VY[src][pidx][tid];
      float sp = orient * (dx * (py - p1y) - dy * (px - p1x));
#pragma unroll
      for (int k = 0; k < 8; ++k) {
        const float cx = VX[src][k][tid], cy = VY[src][k][tid];
        const float sc2 = orient * (dx * (cy - p1y) - dy * (cx - p1x));
        const bool cin = (sc2 >= 0.0f), pin = (sp >= 0.0f);
        const float denom = sp - sc2;
        const float dd = (fabsf(denom) > 1e-9f) ? denom : 1e-9f;
        const float t = sp / dd;
        const float ipx = px + t * (cx - px);
        const float ipy = py + t * (cy - py);
        const bool vk = (k < n);
        const bool e1 = vk && (cin != pin);
        if (e1 && cnt < 8) { VX[dst][cnt][tid] = ipx; VY[dst][cnt][tid] = ipy; }
        cnt += e1 ? 1 : 0;                     // cnt may pass 8: writes dropped (mode='drop')
        const bool e2 = vk && cin;
        if (e2 && cnt < 8) { VX[dst][cnt][tid] = cx; VY[dst][cnt][tid] = cy; }
        cnt += e2 ? 1 : 0;
        px = cx; py = cy; sp = sc2;            // prev == V[k-1]; identical value reuse
      }
      n = cnt;
    }
    // shoelace on final buffer (buf 0 after 4 ping-pongs)
    float a = 0.0f;
#pragma unroll
    for (int k = 0; k < 8; ++k) {
      int nxt = (k == n - 1) ? 0 : ((k + 1 > 7) ? 7 : (k + 1));  // clamp like JAX
      const float xk = VX[0][k][tid], yk = VY[0][k][tid];
      const float xn = VX[0][nxt][tid], yn = VY[0][nxt][tid];
      const float term = xk * yn - xn * yk;
      a += (k < n) ? term : 0.0f;
    }
    const float inter = 0.5f * fabsf(a);
    float aA = ax0 * ay1 - ax1 * ay0;
    aA += ax1 * ay2 - ax2 * ay1;
    aA += ax2 * ay3 - ax3 * ay2;
    aA += ax3 * ay0 - ax0 * ay3;
    const float areaA = 0.5f * fabsf(aA);
    const float areaB = 0.5f * fabsf(sB);
    const float uni = areaA + areaB - inter;
    const float iou = inter / fmaxf(uni, 1e-9f);
    hit = iou > 0.5f;
  }
  const unsigned long long ball = __ballot(hit);
  if ((tid & 63) == 0) {
    const int jw = blockIdx.x * (BSC / 64) + (tid >> 6);
    MT[((size_t)b * NW + jw) * T_CAND + i] = ball;   // transposed: column-major for NMS
  }
}

// ---------------- Kernel 4: greedy NMS via dense masked column-gather + emit -------
// 1024 threads/batch. 16 waves stage MT[b] (96 KB) into LDS; wave 0 resolves:
// per block q, S_q = OR over prior kept rows of their word-q — computed as a dense
// masked gather over ALL prior rows (keep-mask expand), OR-butterfly across lanes.
// Wave-0 memory ops: ~105 ds_reads total (vs 12.5K global loads in R2/R3 — the
// measured per-wave issue bottleneck at ~15 cyc/load).
__global__ __launch_bounds__(1024) void nms_out_kernel(const unsigned long long* __restrict__ MT,
    const float* __restrict__ sPoly, const float* __restrict__ sSc,
    const unsigned* __restrict__ sValid, float* __restrict__ out) {
  __shared__ __align__(16) unsigned long long mt[NW * T_CAND];  // 95,872 B
  __shared__ unsigned long long vb[16];
  __shared__ unsigned long long kw[NW];
  const int b = blockIdx.x;
  const int tid = threadIdx.x;
  const int wave = tid >> 6, lane = tid & 63;

  // stage MT[b] into LDS, 16 waves, b128 vectors (6 loads/thread)
  {
    const ulonglong2* g2 = (const ulonglong2*)(MT + (size_t)b * NW * T_CAND);
    ulonglong2* l2 = (ulonglong2*)mt;
    for (int t = tid; t < NW * T_CAND / 2; t += 1024) l2[t] = g2[t];
  }
  // per-block valid ballots: wave w covers rows w*64..w*64+63 == block w
  if (wave < NW) {
    const int idx = wave * 64 + lane;
    const bool v = (idx < T_CAND) && (sValid[b * T_CAND + idx] != 0u);
    const unsigned long long ball = __ballot(v);
    if (lane == 0) vb[wave] = ball;
  }
  __syncthreads();

  if (wave == 0) {
    unsigned long long kwreg = 0ULL;   // lane q holds keep-word of resolved block q
    for (int q = 0; q < NW; ++q) {
      const unsigned long long* col = &mt[q * T_CAND];
      // own-row word q (clamp OOB lanes of last partial block; never consumed)
      const int nrow = q * 64 + lane;
      const unsigned long long sup = col[nrow < T_CAND ? nrow : (T_CAND - 1)];
      // S_q: dense masked gather over prior rows (1-deep software pipeline)
      unsigned long long acc = 0ULL;
      unsigned long long nxt = (q > 0) ? col[lane] : 0ULL;
      for (int wp = 0; wp < q; ++wp) {
        const unsigned long long row = nxt;
        if (wp + 1 < q) nxt = col[(wp + 1) * 64 + lane];
        const unsigned long long kword = readlane64(kwreg, wp);
        acc |= ((kword >> lane) & 1ULL) ? row : 0ULL;
      }
      // OR-butterfly across 64 lanes -> uniform S_q in all lanes
#pragma unroll
      for (int m = 1; m < 64; m <<= 1)
        acc |= (unsigned long long)__shfl_xor((long long)acc, m, 64);
      unsigned long long keep = vb[q] & ~acc;
      // serial greedy over surviving set bits only (diagonal bit is 0: j>i only)
      unsigned long long alive = keep, rem = keep;
      while (rem) {
        const int s = (int)__builtin_ctzll(rem);
        alive &= ~readlane64(sup, s);
        rem = (rem & (rem - 1)) & alive;
      }
      if (lane == q) kwreg = alive;
      if (lane == 0) kw[q] = alive;
    }
  }
  __syncthreads();

  // emit top-100 (threads 0..99)
  if (tid < 100) {
    const int o = tid;
    int totalKeep = 0;
    for (int w = 0; w < NW; ++w) totalKeep += __popcll(kw[w]);
    const bool kept = o < totalKeep;
    int idx = 0;
    if (kept) {
      int r = o, w = 0;
      unsigned long long word = 0ULL;
      for (; w < NW; ++w) {
        word = kw[w];
        const int c = __popcll(word);
        if (r < c) break;
        r -= c;
      }
      for (int p = 0; p < r; ++p) word &= word - 1;
      idx = w * 64 + (__ffsll(word) - 1);
    } else {
      int r = o - totalKeep, w = 0;
      unsigned long long word = 0ULL;
      for (; w < NW; ++w) {
        const unsigned long long mk = (w == NW - 1) ? ((1ULL << (T_CAND - 64 * (NW - 1))) - 1ULL)
                                                    : ~0ULL;
        word = (~kw[w]) & mk;
        const int c = __popcll(word);
        if (r < c) break;
        r -= c;
      }
      for (int p = 0; p < r; ++p) word &= word - 1;
      idx = w * 64 + (__ffsll(word) - 1);
    }
    const float4* pp = (const float4*)(sPoly + (size_t)(b * T_CAND + idx) * 8);
    float4* ob2 = (float4*)(out + (size_t)b * 800 + (size_t)o * 8);
    ob2[0] = pp[0];
    ob2[1] = pp[1];
    out[1600 + b * 100 + o] = kept ? sSc[b * T_CAND + idx] : 0.0f;  // where(ok, top_s, 0)
    out[1800 + b * 100 + o] = 1.0f;                                 // labels always 1 (C=1)
    out[2000 + b * 100 + o] = kept ? 1.0f : 0.0f;                   // ok
  }
}

extern "C" void kernel_launch(void* const* d_in, const int* in_sizes, int n_in,
                              void* d_out, int out_size, void* d_ws, size_t ws_size,
                              hipStream_t stream) {
  (void)n_in; (void)out_size; (void)ws_size;
  LevelPtrs P;
  // setup_inputs() dict order is interleaved per level; detect defensively via sizes.
  const bool interleaved = (in_sizes[2] == 204800);
  for (int l = 0; l < 5; ++l) {
    if (interleaved) {
      P.loc[l] = (const float*)d_in[4 * l + 0];
      P.cls[l] = (const float*)d_in[4 * l + 1];
      P.reg[l] = (const float*)d_in[4 * l + 2];
    } else {
      P.loc[l] = (const float*)d_in[l];
      P.cls[l] = (const float*)d_in[5 + l];
      P.reg[l] = (const float*)d_in[10 + l];
    }
  }
  P.img = (const int*)d_in[20];

  char* ws = (char*)d_ws;
  float*    candPoly  = (float*)(ws + 0);          // 2*856*8*4 = 54784
  float*    candSc    = (float*)(ws + 54784);      // 6848
  unsigned* candValid = (unsigned*)(ws + 61632);   // 6848
  float*    sPoly     = (float*)(ws + 68480);      // 54784 (16B aligned)
  float*    sSc       = (float*)(ws + 123264);     // 6848
  unsigned* sValid    = (unsigned*)(ws + 130112);  // 6848
  unsigned long long* MT = (unsigned long long*)(ws + 136960); // 2*14*856*8 = 191744 (16B aligned)

  topk_kernel<<<dim3(10), dim3(1024), 0, stream>>>(P, candPoly, candSc, candValid);
  sort_kernel<<<dim3(2), dim3(1024), 0, stream>>>(candPoly, candSc, candValid, sPoly, sSc, sValid);
  iou_kernel<<<dim3(7, T_CAND, 2), dim3(BSC), 0, stream>>>(sPoly, sValid, MT);
  nms_out_kernel<<<dim3(2), dim3(1024), 0, stream>>>(MT, sPoly, sSc, sValid, (float*)d_out);
}

// Round 5
// 79.961 us; speedup vs baseline: 4.8401x; 1.6037x over previous
//
#include <hip/hip_runtime.h>

#pragma clang fp contract(off)

#define T_CAND 856
#define NW 14          // ceil(856/64)
#define BSC 128        // iou kernel block
#define NSH 16         // sub-histograms (split by (tid>>2)&15 to cut same-address atomics)
#define HSTR 513       // sub-hist stride in words (odd -> banks spread)

__device__ const int d_HW[5]  = {12800, 3200, 800, 208, 56};
__device__ const int d_K[5]   = {200, 200, 200, 200, 56};
__device__ const int d_OFF[5] = {0, 200, 400, 600, 800};

struct LevelPtrs {
  const float* loc[5];
  const float* cls[5];
  const float* reg[5];
  const int*   img;
};

__device__ __forceinline__ unsigned long long readlane64(unsigned long long v, int lane) {
  const unsigned lo = (unsigned)__builtin_amdgcn_readlane((int)(unsigned)(v & 0xFFFFFFFFULL), lane);
  const unsigned hi = (unsigned)__builtin_amdgcn_readlane((int)(unsigned)(v >> 32), lane);
  return ((unsigned long long)hi << 32) | lo;
}
__device__ __forceinline__ unsigned long long rfl64(unsigned long long v) {
  const unsigned lo = (unsigned)__builtin_amdgcn_readfirstlane((int)(unsigned)(v & 0xFFFFFFFFULL));
  const unsigned hi = (unsigned)__builtin_amdgcn_readfirstlane((int)(unsigned)(v >> 32));
  return ((unsigned long long)hi << 32) | lo;
}

// ---------------- Kernel 1: per (batch,level) stable top-K + decode ----------------
// Histogram radix-select over score-bits buckets, gather candidates >= cutoff bucket,
// then exact rank-by-counting of unique 64-bit keys (score_bits<<32 | ~idx).
// Rank-by-count of unique keys == stable descending sort permutation (validated R1/R2).
__global__ __launch_bounds__(1024) void topk_kernel(LevelPtrs P,
    float* __restrict__ candPoly, float* __restrict__ candSc, unsigned* __restrict__ candValid) {
  __shared__ unsigned hist[NSH * HSTR];      // ~32.8 KB
  __shared__ unsigned histT[512];
  __shared__ __align__(16) unsigned long long gbuf[1024];  // 8 KB
  __shared__ int gcount;
  __shared__ int cutB;
  const int blk = blockIdx.x;
  const int b = blk / 5, l = blk % 5;
  const int HW = d_HW[l], K = d_K[l], OFF = d_OFF[l];
  const float* cls = P.cls[l] + (size_t)b * HW;
  const float* reg = P.reg[l] + (size_t)b * 8 * HW;
  const float* loc = P.loc[l];
  const int tid = threadIdx.x;

  for (int t = tid; t < NSH * HSTR; t += 1024) hist[t] = 0u;
  if (tid == 0) gcount = 0;
  __syncthreads();

  // pass 1: histogram of masked-score high bits (bucket = bits[31:21], max 0x1FC)
  const int sh = (tid >> 2) & (NSH - 1);
  for (int idx = tid; idx < HW; idx += 1024) {
    const float x = cls[idx];
    // correctly-rounded f32 sigmoid via double (bit-matched XLA in R1 — do not change)
    const float s = (float)(1.0 / (1.0 + exp(-(double)x)));
    const float m = (s > 0.05f) ? s : 0.0f;
    atomicAdd(&hist[sh * HSTR + (__float_as_uint(m) >> 21)], 1u);
  }
  __syncthreads();
  for (int t = tid; t < 512; t += 1024) {
    unsigned sum = 0;
#pragma unroll
    for (int h = 0; h < NSH; ++h) sum += hist[h * HSTR + t];
    histT[t] = sum;
  }
  __syncthreads();
  if (tid == 0) {
    int acc = 0, bx = 511;
    for (; bx >= 0; --bx) { acc += (int)histT[bx]; if (acc >= K) break; }
    cutB = (bx < 0) ? 0 : bx;   // total count == HW >= K, so break always fires
  }
  __syncthreads();

  // pass 2: gather all elements in buckets >= cutB (expect ~K..~2.5K of them, <= 1024)
  const int cb = cutB;
  for (int idx = tid; idx < HW; idx += 1024) {
    const float x = cls[idx];
    const float s = (float)(1.0 / (1.0 + exp(-(double)x)));
    const float m = (s > 0.05f) ? s : 0.0f;
    const unsigned kb = __float_as_uint(m);
    if ((int)(kb >> 21) >= cb) {
      const int pos = atomicAdd(&gcount, 1);
      if (pos < 1024)
        gbuf[pos] = ((unsigned long long)kb << 32)
                  | (unsigned long long)(0xFFFFFFFFu - (unsigned)idx); // tie -> lower idx first
    }
  }
  __syncthreads();
  const int G = min(gcount, 1024);
  if (tid < 4 && G + tid < 1024) gbuf[G + tid] = 0ULL;   // pad so vector loop reads zeros
  __syncthreads();

  // rank-by-count + decode (vectorized LDS reads; pad keys 0 never count: any real key > 0)
  if (tid < G) {
    const unsigned long long my = gbuf[tid];
    const int G4 = (G + 3) & ~3;
    int rank = 0;
    const ulonglong2* g2 = (const ulonglong2*)gbuf;
    for (int j = 0; j < G4 / 2; j += 2) {
      const ulonglong2 a = g2[j], c = g2[j + 1];
      rank += (a.x > my) ? 1 : 0;
      rank += (a.y > my) ? 1 : 0;
      rank += (c.x > my) ? 1 : 0;
      rank += (c.y > my) ? 1 : 0;
    }
    if (rank < K) {
      const float val = __uint_as_float((unsigned)(my >> 32));
      const int idx = (int)(0xFFFFFFFFu - (unsigned)(my & 0xFFFFFFFFULL));
      const float hh = (float)P.img[b * 2 + 0];
      const float ww = (float)P.img[b * 2 + 1];
      const float xmax = ww - 1.0f, ymax = hh - 1.0f;
      const float lx = loc[idx * 2 + 0], ly = loc[idx * 2 + 1];
      const int go = b * T_CAND + OFF + rank;
#pragma unroll
      for (int q = 0; q < 4; ++q) {
        const float rx = reg[(2 * q + 0) * HW + idx];
        const float ry = reg[(2 * q + 1) * HW + idx];
        const float pxv = fminf(fmaxf(lx - rx, 0.0f), xmax);
        const float pyv = fminf(fmaxf(ly - ry, 0.0f), ymax);
        candPoly[go * 8 + 2 * q + 0] = pxv;
        candPoly[go * 8 + 2 * q + 1] = pyv;
      }
      const bool v = (val > 0.05f);   // bw/bh >= MIN_SIZE(0) always true after clip
      candSc[go]    = v ? sqrtf(val) : 0.0f;
      candValid[go] = v ? 1u : 0u;
    }
  }
}

// ---------------- Kernel 2: per-batch stable descending sort of 856 candidates -----
// rank-by-count of unique keys == exact stable sort permutation.
__global__ __launch_bounds__(1024) void sort_kernel(
    const float* __restrict__ candPoly, const float* __restrict__ candSc,
    const unsigned* __restrict__ candValid,
    float* __restrict__ sPoly, float* __restrict__ sSc, unsigned* __restrict__ sValid) {
  __shared__ __align__(16) unsigned long long key[T_CAND];
  const int b = blockIdx.x, tid = threadIdx.x;
  float sc = 0.0f;
  if (tid < T_CAND) {
    sc = candSc[b * T_CAND + tid];
    key[tid] = ((unsigned long long)__float_as_uint(sc) << 32)
             | (unsigned long long)(0xFFFFFFFFu - (unsigned)tid);
  }
  __syncthreads();
  if (tid < T_CAND) {
    const unsigned long long my = key[tid];
    int rank = 0;
    const ulonglong2* k2 = (const ulonglong2*)key;
    for (int j = 0; j < T_CAND / 2; j += 2) {   // 856/4 = 214 iters, 2x ds_read_b128
      const ulonglong2 a = k2[j], c = k2[j + 1];
      rank += (a.x > my) ? 1 : 0;
      rank += (a.y > my) ? 1 : 0;
      rank += (c.x > my) ? 1 : 0;
      rank += (c.y > my) ? 1 : 0;
    }
    sSc[b * T_CAND + rank]    = sc;
    sValid[b * T_CAND + rank] = candValid[b * T_CAND + tid];
    const float4* src = (const float4*)(candPoly + (size_t)(b * T_CAND + tid) * 8);
    float4* dst = (float4*)(sPoly + (size_t)(b * T_CAND + rank) * 8);
    dst[0] = src[0];
    dst[1] = src[1];
  }
}

// ---------------- Kernel 3: suppression bit-matrix via polygon-clip IoU ------------
// TRANSPOSED layout: MT[(b*NW + jw)*856 + i] bit j%64: IoU(A=q[i], B=q[j]) > 0.5,
// only for j>i, both valid.
__global__ __launch_bounds__(BSC) void iou_kernel(const float* __restrict__ sPoly,
                                                  const unsigned* __restrict__ sValid,
                                                  unsigned long long* __restrict__ MT) {
  __shared__ float VX[2][8][BSC];
  __shared__ float VY[2][8][BSC];
  const int i = blockIdx.y, b = blockIdx.z;
  const int tid = threadIdx.x;
  // triangular skip: whole block has j <= i -> all bits 0 (write dense zeros, gather reads them)
  if (blockIdx.x * BSC + (BSC - 1) <= (unsigned)i) {
    if ((tid & 63) == 0) {
      const int jw = blockIdx.x * (BSC / 64) + (tid >> 6);
      MT[((size_t)b * NW + jw) * T_CAND + i] = 0ULL;
    }
    return;
  }
  if (sValid[b * T_CAND + i] == 0u) return;   // row never applied in NMS; skip (uniform)
  const int j = blockIdx.x * BSC + tid;
  const float4* Ap4 = (const float4*)(sPoly + (size_t)(b * T_CAND + i) * 8);
  const float4 a01 = Ap4[0], a23 = Ap4[1];
  const float ax0 = a01.x, ay0 = a01.y, ax1 = a01.z, ay1 = a01.w,
              ax2 = a23.x, ay2 = a23.y, ax3 = a23.z, ay3 = a23.w;
  const int jc = (j < T_CAND) ? j : (T_CAND - 1);
  const float4* Bp4 = (const float4*)(sPoly + (size_t)(b * T_CAND + jc) * 8);
  const float4 b01 = Bp4[0], b23 = Bp4[1];
  const float bx0 = b01.x, by0 = b01.y, bx1 = b01.z, by1 = b01.w,
              bx2 = b23.x, by2 = b23.y, bx3 = b23.z, by3 = b23.w;
  const bool need = (j > i) && (j < T_CAND) && (sValid[b * T_CAND + jc] != 0u);
  // AABB quick-reject: disjoint AABBs => intersection polygon empty => inter == 0 exactly
  // => iou == 0 => hit false, bit-identical to running the clip. Touching AABBs run full path.
  const float aminx = fminf(fminf(ax0, ax1), fminf(ax2, ax3));
  const float amaxx = fmaxf(fmaxf(ax0, ax1), fmaxf(ax2, ax3));
  const float aminy = fminf(fminf(ay0, ay1), fminf(ay2, ay3));
  const float amaxy = fmaxf(fmaxf(ay0, ay1), fmaxf(ay2, ay3));
  const float bminx = fminf(fminf(bx0, bx1), fminf(bx2, bx3));
  const float bmaxx = fmaxf(fmaxf(bx0, bx1), fmaxf(bx2, bx3));
  const float bminy = fminf(fminf(by0, by1), fminf(by2, by3));
  const float bmaxy = fmaxf(fmaxf(by0, by1), fmaxf(by2, by3));
  const bool ov = !(amaxx < bminx || bmaxx < aminx || amaxy < bminy || bmaxy < aminy);
  bool hit = false;
  if (need && ov) {
    // signed 2*area of B (same term order as reference) -> orientation
    float sB = bx0 * by1 - bx1 * by0;
    sB += bx1 * by2 - bx2 * by1;
    sB += bx2 * by3 - bx3 * by2;
    sB += bx3 * by0 - bx0 * by3;
    const float orient = (sB >= 0.0f) ? 1.0f : -1.0f;

    VX[0][0][tid] = ax0; VY[0][0][tid] = ay0;
    VX[0][1][tid] = ax1; VY[0][1][tid] = ay1;
    VX[0][2][tid] = ax2; VY[0][2][tid] = ay2;
    VX[0][3][tid] = ax3; VY[0][3][tid] = ay3;
    int n = 4;
    const float bex[5] = {bx0, bx1, bx2, bx3, bx0};
    const float bey[5] = {by0, by1, by2, by3, by0};
#pragma unroll
    for (int e = 0; e < 4; ++e) {
      const int src = e & 1, dst = src ^ 1;
      const float p1x = bex[e], p1y = bey[e];
      const float dx = bex[e + 1] - p1x, dy = bey[e + 1] - p1y;
      int cnt = 0;
      int pidx = n - 1;                       // JAX gather clamps (incl. -1 -> 0)
      pidx = pidx < 0 ? 0 : (pidx > 7 ? 7 : pidx);
      float px = VX[src][pidx][tid], py = VY[src][pidx][tid];
      float sp = orient * (dx * (py - p1y) - dy * (px - p1x));
#pragma unroll
      for (int k = 0; k < 8; ++k) {
        const float cx = VX[src][k][tid], cy = VY[src][k][tid];
        const float sc2 = orient * (dx * (cy - p1y) - dy * (cx - p1x));
        const bool cin = (sc2 >= 0.0f), pin = (sp >= 0.0f);
        const float denom = sp - sc2;
        const float dd = (fabsf(denom) > 1e-9f) ? denom : 1e-9f;
        const float t = sp / dd;
        const float ipx = px + t * (cx - px);
        const float ipy = py + t * (cy - py);
        const bool vk = (k < n);
        const bool e1 = vk && (cin != pin);
        if (e1 && cnt < 8) { VX[dst][cnt][tid] = ipx; VY[dst][cnt][tid] = ipy; }
        cnt += e1 ? 1 : 0;                     // cnt may pass 8: writes dropped (mode='drop')
        const bool e2 = vk && cin;
        if (e2 && cnt < 8) { VX[dst][cnt][tid] = cx; VY[dst][cnt][tid] = cy; }
        cnt += e2 ? 1 : 0;
        px = cx; py = cy; sp = sc2;            // prev == V[k-1]; identical value reuse
      }
      n = cnt;
    }
    // shoelace on final buffer (buf 0 after 4 ping-pongs)
    float a = 0.0f;
#pragma unroll
    for (int k = 0; k < 8; ++k) {
      int nxt = (k == n - 1) ? 0 : ((k + 1 > 7) ? 7 : (k + 1));  // clamp like JAX
      const float xk = VX[0][k][tid], yk = VY[0][k][tid];
      const float xn = VX[0][nxt][tid], yn = VY[0][nxt][tid];
      const float term = xk * yn - xn * yk;
      a += (k < n) ? term : 0.0f;
    }
    const float inter = 0.5f * fabsf(a);
    float aA = ax0 * ay1 - ax1 * ay0;
    aA += ax1 * ay2 - ax2 * ay1;
    aA += ax2 * ay3 - ax3 * ay2;
    aA += ax3 * ay0 - ax0 * ay3;
    const float areaA = 0.5f * fabsf(aA);
    const float areaB = 0.5f * fabsf(sB);
    const float uni = areaA + areaB - inter;
    const float iou = inter / fmaxf(uni, 1e-9f);
    hit = iou > 0.5f;
  }
  const unsigned long long ball = __ballot(hit);
  if ((tid & 63) == 0) {
    const int jw = blockIdx.x * (BSC / 64) + (tid >> 6);
    MT[((size_t)b * NW + jw) * T_CAND + i] = ball;   // transposed: column-major for NMS
  }
}

// ---------------- Kernel 4a: greedy NMS resolve (scalarized, suppressor-only) ------
// 16 waves stage MT[b] (96 KB) into LDS; wave 0 resolves with all masks in SGPRs.
// Serial loop visits only lanes whose intra-block sup word != 0 (no-op lanes skipped;
// provably identical result). Writes kw[b][14] to workspace.
__global__ __launch_bounds__(1024) void nms_resolve_kernel(const unsigned long long* __restrict__ MT,
    const unsigned* __restrict__ sValid, unsigned long long* __restrict__ kwOut) {
  __shared__ __align__(16) unsigned long long mt[NW * T_CAND];  // 95,872 B
  __shared__ unsigned long long vb[16];
  const int b = blockIdx.x;
  const int tid = threadIdx.x;
  const int wave = tid >> 6, lane = tid & 63;

  // stage MT[b] into LDS, 16 waves, b128 vectors (6 loads/thread)
  {
    const ulonglong2* g2 = (const ulonglong2*)(MT + (size_t)b * NW * T_CAND);
    ulonglong2* l2 = (ulonglong2*)mt;
    for (int t = tid; t < NW * T_CAND / 2; t += 1024) l2[t] = g2[t];
  }
  // per-block valid ballots: wave w covers rows w*64..w*64+63 == block w
  if (wave < NW) {
    const int idx = wave * 64 + lane;
    const bool v = (idx < T_CAND) && (sValid[b * T_CAND + idx] != 0u);
    const unsigned long long ball = __ballot(v);
    if (lane == 0) vb[wave] = ball;
  }
  __syncthreads();

  if (wave == 0) {
    unsigned long long kwreg = 0ULL;   // lane q holds keep-word of resolved block q
    for (int q = 0; q < NW; ++q) {
      const unsigned long long* col = &mt[q * T_CAND];
      // own-row word q (clamp OOB lanes of last partial block; never consumed)
      const int nrow = q * 64 + lane;
      const unsigned long long sup = col[nrow < T_CAND ? nrow : (T_CAND - 1)];
      // S_q: dense masked gather over prior rows (keep-mask expand)
      unsigned long long acc = 0ULL;
      for (int wp = 0; wp < q; ++wp) {
        const unsigned long long row = col[wp * 64 + lane];
        const unsigned long long kword = readlane64(kwreg, wp);
        acc |= ((kword >> lane) & 1ULL) ? row : 0ULL;
      }
      // OR-butterfly across 64 lanes -> uniform S_q
#pragma unroll
      for (int m = 1; m < 64; m <<= 1)
        acc |= (unsigned long long)__shfl_xor((long long)acc, m, 64);
      const unsigned long long S = rfl64(acc);                  // -> SGPR
      const unsigned long long validq = rfl64(vb[q]);           // -> SGPR
      unsigned long long alive = validq & ~S;
      // suppressor-only serial greedy: lanes with sup==0 are no-ops, skip them entirely
      const unsigned long long suppr = __ballot(sup != 0ULL);   // SGPR
      unsigned long long rem = alive & suppr;
      while (rem) {
        const int s = (int)__builtin_ctzll(rem);
        rem &= rem - 1;
        if ((alive >> s) & 1ULL) {
          alive &= ~readlane64(sup, s);
          rem &= alive;
        }
      }
      if (lane == q) kwreg = alive;
    }
    if (lane < NW) kwOut[b * NW + lane] = kwreg;
  }
}

// ---------------- Kernel 4b: top-100 emit ------------------------------------------
__global__ __launch_bounds__(128) void nms_emit_kernel(const unsigned long long* __restrict__ kwOut,
    const float* __restrict__ sPoly, const float* __restrict__ sSc, float* __restrict__ out) {
  const int b = blockIdx.x, tid = threadIdx.x;
  __shared__ unsigned long long kw[NW];
  if (tid < NW) kw[tid] = kwOut[b * NW + tid];
  __syncthreads();
  if (tid < 100) {
    const int o = tid;
    int totalKeep = 0;
    for (int w = 0; w < NW; ++w) totalKeep += __popcll(kw[w]);
    const bool kept = o < totalKeep;
    int idx = 0;
    if (kept) {
      int r = o, w = 0;
      unsigned long long word = 0ULL;
      for (; w < NW; ++w) {
        word = kw[w];
        const int c = __popcll(word);
        if (r < c) break;
        r -= c;
      }
      for (int p = 0; p < r; ++p) word &= word - 1;
      idx = w * 64 + (__ffsll(word) - 1);
    } else {
      int r = o - totalKeep, w = 0;
      unsigned long long word = 0ULL;
      for (; w < NW; ++w) {
        const unsigned long long mk = (w == NW - 1) ? ((1ULL << (T_CAND - 64 * (NW - 1))) - 1ULL)
                                                    : ~0ULL;
        word = (~kw[w]) & mk;
        const int c = __popcll(word);
        if (r < c) break;
        r -= c;
      }
      for (int p = 0; p < r; ++p) word &= word - 1;
      idx = w * 64 + (__ffsll(word) - 1);
    }
    const float4* pp = (const float4*)(sPoly + (size_t)(b * T_CAND + idx) * 8);
    float4* ob2 = (float4*)(out + (size_t)b * 800 + (size_t)o * 8);
    ob2[0] = pp[0];
    ob2[1] = pp[1];
    out[1600 + b * 100 + o] = kept ? sSc[b * T_CAND + idx] : 0.0f;  // where(ok, top_s, 0)
    out[1800 + b * 100 + o] = 1.0f;                                 // labels always 1 (C=1)
    out[2000 + b * 100 + o] = kept ? 1.0f : 0.0f;                   // ok
  }
}

extern "C" void kernel_launch(void* const* d_in, const int* in_sizes, int n_in,
                              void* d_out, int out_size, void* d_ws, size_t ws_size,
                              hipStream_t stream) {
  (void)n_in; (void)out_size; (void)ws_size;
  LevelPtrs P;
  // setup_inputs() dict order is interleaved per level; detect defensively via sizes.
  const bool interleaved = (in_sizes[2] == 204800);
  for (int l = 0; l < 5; ++l) {
    if (interleaved) {
      P.loc[l] = (const float*)d_in[4 * l + 0];
      P.cls[l] = (const float*)d_in[4 * l + 1];
      P.reg[l] = (const float*)d_in[4 * l + 2];
    } else {
      P.loc[l] = (const float*)d_in[l];
      P.cls[l] = (const float*)d_in[5 + l];
      P.reg[l] = (const float*)d_in[10 + l];
    }
  }
  P.img = (const int*)d_in[20];

  char* ws = (char*)d_ws;
  float*    candPoly  = (float*)(ws + 0);          // 2*856*8*4 = 54784
  float*    candSc    = (float*)(ws + 54784);      // 6848
  unsigned* candValid = (unsigned*)(ws + 61632);   // 6848
  float*    sPoly     = (float*)(ws + 68480);      // 54784 (16B aligned)
  float*    sSc       = (float*)(ws + 123264);     // 6848
  unsigned* sValid    = (unsigned*)(ws + 130112);  // 6848
  unsigned long long* MT = (unsigned long long*)(ws + 136960); // 2*14*856*8 = 191744 (16B aligned)
  unsigned long long* kwOut = (unsigned long long*)(ws + 328704); // 2*14*8 = 224

  topk_kernel<<<dim3(10), dim3(1024), 0, stream>>>(P, candPoly, candSc, candValid);
  sort_kernel<<<dim3(2), dim3(1024), 0, stream>>>(candPoly, candSc, candValid, sPoly, sSc, sValid);
  iou_kernel<<<dim3(7, T_CAND, 2), dim3(BSC), 0, stream>>>(sPoly, sValid, MT);
  nms_resolve_kernel<<<dim3(2), dim3(1024), 0, stream>>>(MT, sValid, kwOut);
  nms_emit_kernel<<<dim3(2), dim3(128), 0, stream>>>(kwOut, sPoly, sSc, (float*)d_out);
}

// Round 6
// 75.114 us; speedup vs baseline: 5.1524x; 1.0645x over previous
//
#include <hip/hip_runtime.h>

#pragma clang fp contract(off)

#define T_CAND 856
#define NW 14          // ceil(856/64)
#define NSH 16         // sub-histograms (split by (tid>>2)&15 to cut same-address atomics)
#define HSTR 513       // sub-hist stride in words (odd -> banks spread)

__device__ const int d_HW[5]  = {12800, 3200, 800, 208, 56};
__device__ const int d_K[5]   = {200, 200, 200, 200, 56};
__device__ const int d_OFF[5] = {0, 200, 400, 600, 800};

struct LevelPtrs {
  const float* loc[5];
  const float* cls[5];
  const float* reg[5];
  const int*   img;
};

__device__ __forceinline__ unsigned long long readlane64(unsigned long long v, int lane) {
  const unsigned lo = (unsigned)__builtin_amdgcn_readlane((int)(unsigned)(v & 0xFFFFFFFFULL), lane);
  const unsigned hi = (unsigned)__builtin_amdgcn_readlane((int)(unsigned)(v >> 32), lane);
  return ((unsigned long long)hi << 32) | lo;
}
__device__ __forceinline__ unsigned long long rfl64(unsigned long long v) {
  const unsigned lo = (unsigned)__builtin_amdgcn_readfirstlane((int)(unsigned)(v & 0xFFFFFFFFULL));
  const unsigned hi = (unsigned)__builtin_amdgcn_readfirstlane((int)(unsigned)(v >> 32));
  return ((unsigned long long)hi << 32) | lo;
}

// ---------------- Kernel 1: per (batch,level) stable top-K + decode ----------------
// Histogram radix-select; sigmoid values cached in LDS so the gather pass does no
// double-exp recompute. Rank-by-count of unique keys == stable sort (validated R1+).
__global__ __launch_bounds__(1024) void topk_kernel(LevelPtrs P,
    float* __restrict__ candPoly, float* __restrict__ candSc, unsigned* __restrict__ candValid) {
  __shared__ unsigned hist[NSH * HSTR];      // ~32.8 KB
  __shared__ unsigned histT[512];
  __shared__ __align__(16) unsigned long long gbuf[1024];  // 8 KB
  __shared__ float mcache[12800];            // 51.2 KB (max HW)
  __shared__ int gcount;
  __shared__ int cutB;
  const int blk = blockIdx.x;
  const int b = blk / 5, l = blk % 5;
  const int HW = d_HW[l], K = d_K[l], OFF = d_OFF[l];
  const float* cls = P.cls[l] + (size_t)b * HW;
  const float* reg = P.reg[l] + (size_t)b * 8 * HW;
  const float* loc = P.loc[l];
  const int tid = threadIdx.x;

  for (int t = tid; t < NSH * HSTR; t += 1024) hist[t] = 0u;
  if (tid == 0) gcount = 0;
  __syncthreads();

  // pass 1: sigmoid + cache + histogram of masked-score high bits (bucket = bits[31:21])
  const int sh = (tid >> 2) & (NSH - 1);
  for (int idx = tid; idx < HW; idx += 1024) {
    const float x = cls[idx];
    // correctly-rounded f32 sigmoid via double (bit-matched XLA in R1 — do not change)
    const float s = (float)(1.0 / (1.0 + exp(-(double)x)));
    const float m = (s > 0.05f) ? s : 0.0f;
    mcache[idx] = m;
    atomicAdd(&hist[sh * HSTR + (__float_as_uint(m) >> 21)], 1u);
  }
  __syncthreads();
  for (int t = tid; t < 512; t += 1024) {
    unsigned sum = 0;
#pragma unroll
    for (int h = 0; h < NSH; ++h) sum += hist[h * HSTR + t];
    histT[t] = sum;
  }
  __syncthreads();
  if (tid == 0) {
    int acc = 0, bx = 511;
    for (; bx >= 0; --bx) { acc += (int)histT[bx]; if (acc >= K) break; }
    cutB = (bx < 0) ? 0 : bx;   // total count == HW >= K, so break always fires
  }
  __syncthreads();

  // pass 2: gather all elements in buckets >= cutB from cache (<= 1024, validated R2+)
  const int cb = cutB;
  for (int idx = tid; idx < HW; idx += 1024) {
    const unsigned kb = __float_as_uint(mcache[idx]);
    if ((int)(kb >> 21) >= cb) {
      const int pos = atomicAdd(&gcount, 1);
      if (pos < 1024)
        gbuf[pos] = ((unsigned long long)kb << 32)
                  | (unsigned long long)(0xFFFFFFFFu - (unsigned)idx); // tie -> lower idx first
    }
  }
  __syncthreads();
  const int G = min(gcount, 1024);
  if (tid < 4 && G + tid < 1024) gbuf[G + tid] = 0ULL;   // pad so vector loop reads zeros
  __syncthreads();

  // rank-by-count + decode (vectorized LDS reads; pad keys 0 never count: any real key > 0)
  if (tid < G) {
    const unsigned long long my = gbuf[tid];
    const int G4 = (G + 3) & ~3;
    int rank = 0;
    const ulonglong2* g2 = (const ulonglong2*)gbuf;
    for (int j = 0; j < G4 / 2; j += 2) {
      const ulonglong2 a = g2[j], c = g2[j + 1];
      rank += (a.x > my) ? 1 : 0;
      rank += (a.y > my) ? 1 : 0;
      rank += (c.x > my) ? 1 : 0;
      rank += (c.y > my) ? 1 : 0;
    }
    if (rank < K) {
      const float val = __uint_as_float((unsigned)(my >> 32));
      const int idx = (int)(0xFFFFFFFFu - (unsigned)(my & 0xFFFFFFFFULL));
      const float hh = (float)P.img[b * 2 + 0];
      const float ww = (float)P.img[b * 2 + 1];
      const float xmax = ww - 1.0f, ymax = hh - 1.0f;
      const float lx = loc[idx * 2 + 0], ly = loc[idx * 2 + 1];
      const int go = b * T_CAND + OFF + rank;
#pragma unroll
      for (int q = 0; q < 4; ++q) {
        const float rx = reg[(2 * q + 0) * HW + idx];
        const float ry = reg[(2 * q + 1) * HW + idx];
        const float pxv = fminf(fmaxf(lx - rx, 0.0f), xmax);
        const float pyv = fminf(fmaxf(ly - ry, 0.0f), ymax);
        candPoly[go * 8 + 2 * q + 0] = pxv;
        candPoly[go * 8 + 2 * q + 1] = pyv;
      }
      const bool v = (val > 0.05f);   // bw/bh >= MIN_SIZE(0) always true after clip
      candSc[go]    = v ? sqrtf(val) : 0.0f;
      candValid[go] = v ? 1u : 0u;
    }
  }
}

// ---------------- Kernel 2: per-batch stable sort + AABB emit + counter zero -------
__global__ __launch_bounds__(1024) void sort_kernel(
    const float* __restrict__ candPoly, const float* __restrict__ candSc,
    const unsigned* __restrict__ candValid,
    float* __restrict__ sPoly, float* __restrict__ sSc, unsigned* __restrict__ sValid,
    float* __restrict__ sAABB, unsigned* __restrict__ pairCount) {
  __shared__ __align__(16) unsigned long long key[T_CAND];
  const int b = blockIdx.x, tid = threadIdx.x;
  if (b == 0 && tid == 0) *pairCount = 0u;   // consumed by aabb_pairs (next launch)
  float sc = 0.0f;
  if (tid < T_CAND) {
    sc = candSc[b * T_CAND + tid];
    key[tid] = ((unsigned long long)__float_as_uint(sc) << 32)
             | (unsigned long long)(0xFFFFFFFFu - (unsigned)tid);
  }
  __syncthreads();
  if (tid < T_CAND) {
    const unsigned long long my = key[tid];
    int rank = 0;
    const ulonglong2* k2 = (const ulonglong2*)key;
    for (int j = 0; j < T_CAND / 2; j += 2) {
      const ulonglong2 a = k2[j], c = k2[j + 1];
      rank += (a.x > my) ? 1 : 0;
      rank += (a.y > my) ? 1 : 0;
      rank += (c.x > my) ? 1 : 0;
      rank += (c.y > my) ? 1 : 0;
    }
    sSc[b * T_CAND + rank]    = sc;
    sValid[b * T_CAND + rank] = candValid[b * T_CAND + tid];
    const float4* src = (const float4*)(candPoly + (size_t)(b * T_CAND + tid) * 8);
    const float4 s0 = src[0], s1 = src[1];
    float4* dst = (float4*)(sPoly + (size_t)(b * T_CAND + rank) * 8);
    dst[0] = s0;
    dst[1] = s1;
    float4 bb;  // minx,miny,maxx,maxy
    bb.x = fminf(fminf(s0.x, s0.z), fminf(s1.x, s1.z));
    bb.y = fminf(fminf(s0.y, s0.w), fminf(s1.y, s1.w));
    bb.z = fmaxf(fmaxf(s0.x, s0.z), fmaxf(s1.x, s1.z));
    bb.w = fmaxf(fmaxf(s0.y, s0.w), fmaxf(s1.y, s1.w));
    *(float4*)(sAABB + (size_t)(b * T_CAND + rank) * 4) = bb;
  }
}

// ---------------- Kernel 3a: AABB prescreen -> compacted pair list + MT zero -------
// Tile (jt, it, b): 1 wave; lane = j offset. Disjoint AABBs => inter == 0 exactly =>
// no bit (bit-exact, field-validated R3-R5). Overlapping (j>i, both valid) pairs are
// compacted via wave scan + one atomicAdd per tile. All MT words are zero-stored here;
// clip_kernel atomicOr's hit bits on top.
__global__ __launch_bounds__(64) void aabb_pairs_kernel(
    const float* __restrict__ sAABB, const unsigned* __restrict__ sValid,
    unsigned long long* __restrict__ MT, unsigned* __restrict__ pairList,
    unsigned* __restrict__ pairCount) {
  const int jt = blockIdx.x, it = blockIdx.y, b = blockIdx.z;
  const int lane = threadIdx.x;
  const int iRow = it * 64 + lane;
  if (jt < it) {   // whole tile has j < i: zero words only
    if (iRow < T_CAND) MT[((size_t)b * NW + jt) * T_CAND + iRow] = 0ULL;
    return;
  }
  const int j = jt * 64 + lane;
  const int jc = j < T_CAND ? j : T_CAND - 1;
  const float4 jb = *(const float4*)(sAABB + (size_t)(b * T_CAND + jc) * 4);
  const bool jv = (j < T_CAND) && (sValid[b * T_CAND + j] != 0u);
  const int ic = iRow < T_CAND ? iRow : T_CAND - 1;
  const float4 ib = *(const float4*)(sAABB + (size_t)(b * T_CAND + ic) * 4);
  const int iv = (iRow < T_CAND) && (sValid[b * T_CAND + ic] != 0u);
  unsigned long long roww = 0ULL;
  for (int q = 0; q < 64; ++q) {
    const float iminx = __shfl(ib.x, q), iminy = __shfl(ib.y, q);
    const float imaxx = __shfl(ib.z, q), imaxy = __shfl(ib.w, q);
    const int ivq = __shfl(iv, q);
    const int irow_q = it * 64 + q;
    const bool ov = !(imaxx < jb.x || jb.z < iminx || imaxy < jb.y || jb.w < iminy);
    const bool pred = ivq && jv && (j > irow_q) && ov;
    const unsigned long long w = __ballot(pred);
    if (lane == q) roww = w;
  }
  if (iRow < T_CAND) MT[((size_t)b * NW + jt) * T_CAND + iRow] = 0ULL;
  // compact: lane L owns row iRow's word
  const int cnt = __popcll(roww);
  int incl = cnt;
#pragma unroll
  for (int d = 1; d < 64; d <<= 1) {
    const int v = __shfl_up(incl, d);
    if (lane >= d) incl += v;
  }
  const int ex = incl - cnt;
  int base = 0;
  if (lane == 63) base = (int)atomicAdd(pairCount, (unsigned)incl);
  base = __shfl(base, 63);
  unsigned off = (unsigned)(base + ex);
  unsigned long long t = roww;
  while (t) {
    const int jb2 = (int)__builtin_ctzll(t);
    t &= t - 1;
    pairList[off++] = ((unsigned)b << 20) | ((unsigned)iRow << 10) | (unsigned)(jt * 64 + jb2);
  }
}

// ---------------- Kernel 3b: polygon-clip IoU on surviving pairs -------------------
__global__ __launch_bounds__(256) void clip_kernel(
    const unsigned* __restrict__ pairList, const unsigned* __restrict__ pairCount,
    const float* __restrict__ sPoly, unsigned long long* __restrict__ MT) {
  __shared__ float VX[2][8][256];
  __shared__ float VY[2][8][256];
  const int tid = threadIdx.x;
  const unsigned count = *pairCount;
  for (unsigned t0 = blockIdx.x * 256 + tid; t0 < count; t0 += gridDim.x * 256) {
    const unsigned pk = pairList[t0];
    const int b = (pk >> 20) & 1, i = (pk >> 10) & 1023, j = pk & 1023;
    const float4* Ap4 = (const float4*)(sPoly + (size_t)(b * T_CAND + i) * 8);
    const float4 a01 = Ap4[0], a23 = Ap4[1];
    const float ax0 = a01.x, ay0 = a01.y, ax1 = a01.z, ay1 = a01.w,
                ax2 = a23.x, ay2 = a23.y, ax3 = a23.z, ay3 = a23.w;
    const float4* Bp4 = (const float4*)(sPoly + (size_t)(b * T_CAND + j) * 8);
    const float4 b01 = Bp4[0], b23 = Bp4[1];
    const float bx0 = b01.x, by0 = b01.y, bx1 = b01.z, by1 = b01.w,
                bx2 = b23.x, by2 = b23.y, bx3 = b23.z, by3 = b23.w;
    // signed 2*area of B (same term order as reference) -> orientation
    float sB = bx0 * by1 - bx1 * by0;
    sB += bx1 * by2 - bx2 * by1;
    sB += bx2 * by3 - bx3 * by2;
    sB += bx3 * by0 - bx0 * by3;
    const float orient = (sB >= 0.0f) ? 1.0f : -1.0f;

    VX[0][0][tid] = ax0; VY[0][0][tid] = ay0;
    VX[0][1][tid] = ax1; VY[0][1][tid] = ay1;
    VX[0][2][tid] = ax2; VY[0][2][tid] = ay2;
    VX[0][3][tid] = ax3; VY[0][3][tid] = ay3;
    int n = 4;
    const float bex[5] = {bx0, bx1, bx2, bx3, bx0};
    const float bey[5] = {by0, by1, by2, by3, by0};
#pragma unroll
    for (int e = 0; e < 4; ++e) {
      const int src = e & 1, dst = src ^ 1;
      const float p1x = bex[e], p1y = bey[e];
      const float dx = bex[e + 1] - p1x, dy = bey[e + 1] - p1y;
      int cnt = 0;
      int pidx = n - 1;                       // JAX gather clamps (incl. -1 -> 0)
      pidx = pidx < 0 ? 0 : (pidx > 7 ? 7 : pidx);
      float px = VX[src][pidx][tid], py = VY[src][pidx][tid];
      float sp = orient * (dx * (py - p1y) - dy * (px - p1x));
      for (int k = 0; k < 8; ++k) {
        if (k >= n) break;                    // k>=n iterations are provable no-ops
        const float cx = VX[src][k][tid], cy = VY[src][k][tid];
        const float sc2 = orient * (dx * (cy - p1y) - dy * (cx - p1x));
        const bool cin = (sc2 >= 0.0f), pin = (sp >= 0.0f);
        const float denom = sp - sc2;
        const float dd = (fabsf(denom) > 1e-9f) ? denom : 1e-9f;
        const float t = sp / dd;
        const float ipx = px + t * (cx - px);
        const float ipy = py + t * (cy - py);
        const bool e1 = (cin != pin);
        if (e1 && cnt < 8) { VX[dst][cnt][tid] = ipx; VY[dst][cnt][tid] = ipy; }
        cnt += e1 ? 1 : 0;                    // cnt may pass 8: writes dropped (mode='drop')
        if (cin && cnt < 8) { VX[dst][cnt][tid] = cx; VY[dst][cnt][tid] = cy; }
        cnt += cin ? 1 : 0;
        px = cx; py = cy; sp = sc2;           // prev == V[k-1]; identical value reuse
      }
      n = cnt;
    }
    // shoelace on final buffer (buf 0 after 4 ping-pongs)
    float a = 0.0f;
    for (int k = 0; k < 8; ++k) {
      if (k >= n) break;
      const int nxt = (k == n - 1) ? 0 : ((k + 1 > 7) ? 7 : (k + 1));  // clamp like JAX
      const float xk = VX[0][k][tid], yk = VY[0][k][tid];
      const float xn = VX[0][nxt][tid], yn = VY[0][nxt][tid];
      a += xk * yn - xn * yk;
    }
    const float inter = 0.5f * fabsf(a);
    float aA = ax0 * ay1 - ax1 * ay0;
    aA += ax1 * ay2 - ax2 * ay1;
    aA += ax2 * ay3 - ax3 * ay2;
    aA += ax3 * ay0 - ax0 * ay3;
    const float areaA = 0.5f * fabsf(aA);
    const float areaB = 0.5f * fabsf(sB);
    const float uni = areaA + areaB - inter;
    const float iou = inter / fmaxf(uni, 1e-9f);
    if (iou > 0.5f)
      atomicOr(&MT[((size_t)b * NW + (j >> 6)) * T_CAND + i], 1ULL << (j & 63));
  }
}

// ---------------- Kernel 4: greedy NMS resolve (scalarized) + top-100 emit ---------
__global__ __launch_bounds__(1024) void nms_resolve_emit_kernel(
    const unsigned long long* __restrict__ MT, const unsigned* __restrict__ sValid,
    const float* __restrict__ sPoly, const float* __restrict__ sSc, float* __restrict__ out) {
  __shared__ __align__(16) unsigned long long mt[NW * T_CAND];  // 95,872 B
  __shared__ unsigned long long vb[16];
  __shared__ unsigned long long kw[NW];
  const int b = blockIdx.x;
  const int tid = threadIdx.x;
  const int wave = tid >> 6, lane = tid & 63;

  {
    const ulonglong2* g2 = (const ulonglong2*)(MT + (size_t)b * NW * T_CAND);
    ulonglong2* l2 = (ulonglong2*)mt;
    for (int t = tid; t < NW * T_CAND / 2; t += 1024) l2[t] = g2[t];
  }
  if (wave < NW) {
    const int idx = wave * 64 + lane;
    const bool v = (idx < T_CAND) && (sValid[b * T_CAND + idx] != 0u);
    const unsigned long long ball = __ballot(v);
    if (lane == 0) vb[wave] = ball;
  }
  __syncthreads();

  if (wave == 0) {
    unsigned long long kwreg = 0ULL;   // lane q holds keep-word of resolved block q
    for (int q = 0; q < NW; ++q) {
      const unsigned long long* col = &mt[q * T_CAND];
      const int nrow = q * 64 + lane;
      const unsigned long long sup = col[nrow < T_CAND ? nrow : (T_CAND - 1)];
      unsigned long long acc = 0ULL;
      for (int wp = 0; wp < q; ++wp) {
        const unsigned long long row = col[wp * 64 + lane];
        const unsigned long long kword = readlane64(kwreg, wp);
        acc |= ((kword >> lane) & 1ULL) ? row : 0ULL;
      }
#pragma unroll
      for (int m = 1; m < 64; m <<= 1)
        acc |= (unsigned long long)__shfl_xor((long long)acc, m, 64);
      const unsigned long long S = rfl64(acc);
      const unsigned long long validq = rfl64(vb[q]);
      unsigned long long alive = validq & ~S;
      const unsigned long long suppr = __ballot(sup != 0ULL);
      unsigned long long rem = alive & suppr;
      while (rem) {
        const int s = (int)__builtin_ctzll(rem);
        rem &= rem - 1;
        if ((alive >> s) & 1ULL) {
          alive &= ~readlane64(sup, s);
          rem &= alive;
        }
      }
      if (lane == q) kwreg = alive;
    }
    if (lane < NW) kw[lane] = kwreg;
  }
  __syncthreads();

  if (tid < 100) {
    const int o = tid;
    int totalKeep = 0;
    for (int w = 0; w < NW; ++w) totalKeep += __popcll(kw[w]);
    const bool kept = o < totalKeep;
    int idx = 0;
    if (kept) {
      int r = o, w = 0;
      unsigned long long word = 0ULL;
      for (; w < NW; ++w) {
        word = kw[w];
        const int c = __popcll(word);
        if (r < c) break;
        r -= c;
      }
      for (int p = 0; p < r; ++p) word &= word - 1;
      idx = w * 64 + (__ffsll(word) - 1);
    } else {
      int r = o - totalKeep, w = 0;
      unsigned long long word = 0ULL;
      for (; w < NW; ++w) {
        const unsigned long long mk = (w == NW - 1) ? ((1ULL << (T_CAND - 64 * (NW - 1))) - 1ULL)
                                                    : ~0ULL;
        word = (~kw[w]) & mk;
        const int c = __popcll(word);
        if (r < c) break;
        r -= c;
      }
      for (int p = 0; p < r; ++p) word &= word - 1;
      idx = w * 64 + (__ffsll(word) - 1);
    }
    const float4* pp = (const float4*)(sPoly + (size_t)(b * T_CAND + idx) * 8);
    float4* ob2 = (float4*)(out + (size_t)b * 800 + (size_t)o * 8);
    ob2[0] = pp[0];
    ob2[1] = pp[1];
    out[1600 + b * 100 + o] = kept ? sSc[b * T_CAND + idx] : 0.0f;  // where(ok, top_s, 0)
    out[1800 + b * 100 + o] = 1.0f;                                 // labels always 1 (C=1)
    out[2000 + b * 100 + o] = kept ? 1.0f : 0.0f;                   // ok
  }
}

extern "C" void kernel_launch(void* const* d_in, const int* in_sizes, int n_in,
                              void* d_out, int out_size, void* d_ws, size_t ws_size,
                              hipStream_t stream) {
  (void)n_in; (void)out_size; (void)ws_size;
  LevelPtrs P;
  const bool interleaved = (in_sizes[2] == 204800);
  for (int l = 0; l < 5; ++l) {
    if (interleaved) {
      P.loc[l] = (const float*)d_in[4 * l + 0];
      P.cls[l] = (const float*)d_in[4 * l + 1];
      P.reg[l] = (const float*)d_in[4 * l + 2];
    } else {
      P.loc[l] = (const float*)d_in[l];
      P.cls[l] = (const float*)d_in[5 + l];
      P.reg[l] = (const float*)d_in[10 + l];
    }
  }
  P.img = (const int*)d_in[20];

  char* ws = (char*)d_ws;
  float*    candPoly  = (float*)(ws + 0);          // 54784
  float*    candSc    = (float*)(ws + 54784);      // 6848
  unsigned* candValid = (unsigned*)(ws + 61632);   // 6848
  float*    sPoly     = (float*)(ws + 68480);      // 54784 (16B aligned)
  float*    sSc       = (float*)(ws + 123264);     // 6848
  unsigned* sValid    = (unsigned*)(ws + 130112);  // 6848
  unsigned long long* MT = (unsigned long long*)(ws + 136960); // 191744 -> ends 328704
  float*    sAABB     = (float*)(ws + 328704);     // 2*856*4*4 = 27392 -> 356096
  unsigned* pairCount = (unsigned*)(ws + 356096);  // 4 (padded to 356112)
  unsigned* pairList  = (unsigned*)(ws + 356112);  // max 856*855/2*2*4 = 2,927,520 B

  topk_kernel<<<dim3(10), dim3(1024), 0, stream>>>(P, candPoly, candSc, candValid);
  sort_kernel<<<dim3(2), dim3(1024), 0, stream>>>(candPoly, candSc, candValid,
                                                  sPoly, sSc, sValid, sAABB, pairCount);
  aabb_pairs_kernel<<<dim3(NW, NW, 2), dim3(64), 0, stream>>>(sAABB, sValid, MT,
                                                              pairList, pairCount);
  clip_kernel<<<dim3(512), dim3(256), 0, stream>>>(pairList, pairCount, sPoly, MT);
  nms_resolve_emit_kernel<<<dim3(2), dim3(1024), 0, stream>>>(MT, sValid, sPoly, sSc,
                                                              (float*)d_out);
}